// Round 8
// baseline (318.535 us; speedup 1.0000x reference)
//
#include <hip/hip_runtime.h>
#include <hip/hip_bf16.h>

// B=4, S=2048, D=1024, H=16, DK=DV=64. Inputs f32, output f32 (confirmed r8).
// MFMA math bf16 with f32 accum. Round 17:
//  - qkv: embconv stays deleted, but A (f32 emb) is register-PREFETCHED one
//    K-step ahead (issue after mid-barrier, under MFMA; convert+ds_write at
//    next iter top) -- fixes r16's exposed in-iteration load latency.
//    B stays global_load_lds. A staged to padded As[128][40] via ds_write.
//  - flash: reverted to r15 proven structure (128-row q-tile, 512 thr,
//    y->t CU-balancing swizzle, deferred l-sum) -- r16's 64-row pairing
//    doubled staging/barrier volume (528 vs 272 tile-visits/bh).
//  - oproj/wtrans unchanged.

typedef __attribute__((ext_vector_type(8))) short bf16x8;
typedef __attribute__((ext_vector_type(4))) float f32x4;
typedef __attribute__((ext_vector_type(4))) unsigned int u32x4;
typedef __attribute__((ext_vector_type(2))) unsigned int u32x2;

#define MFMA16(a, b, c) __builtin_amdgcn_mfma_f32_16x16x32_bf16((a), (b), (c), 0, 0, 0)

#define LOG2E 1.44269504088896340736f
#define BIG_NEG (-3.0e38f)
#define DEFER_THR 10.0f  // log2-domain; P bounded by 2^10 when rescale skipped

__device__ __forceinline__ unsigned short f2bf(float f) {
  union { float f; unsigned int i; } x; x.f = f;
  unsigned int lsb = (x.i >> 16) & 1;
  x.i += 0x7fffu + lsb;  // RNE (finite inputs only)
  return (unsigned short)(x.i >> 16);
}

__device__ __forceinline__ unsigned int cvtpk(float lo, float hi) {
  unsigned int r;
  asm("v_cvt_pk_bf16_f32 %0, %1, %2" : "=v"(r) : "v"(lo), "v"(hi));
  return r;
}

// global -> LDS direct DMA, 16B per lane. lds dest must be wave-uniform base;
// HW writes base + lane*16. Global src is per-lane.
__device__ __forceinline__ void gl16(const unsigned short* g, void* l) {
  __builtin_amdgcn_global_load_lds(
      (const __attribute__((address_space(1))) unsigned int*)g,
      (__attribute__((address_space(3))) unsigned int*)l, 16, 0, 0);
}

// ---------------------------------------------------------------------------
// Batched transpose + downconvert: in f32 [batch][R][C] -> out bf16 [batch][C][R]
// ---------------------------------------------------------------------------
__global__ void wtrans_kernel(const float* __restrict__ in,
                              unsigned short* __restrict__ out, int R, int C) {
  __shared__ unsigned short tile[32][33];
  const int bz = blockIdx.z;
  const int c0 = blockIdx.x * 32, r0 = blockIdx.y * 32;
  const float* ip = in + (size_t)bz * R * C;
  unsigned short* op = out + (size_t)bz * R * C;
  const int tx = threadIdx.x, ty = threadIdx.y;  // (32, 8)
#pragma unroll
  for (int i = 0; i < 32; i += 8)
    tile[ty + i][tx] = f2bf(ip[(size_t)(r0 + ty + i) * C + (c0 + tx)]);
  __syncthreads();
#pragma unroll
  for (int i = 0; i < 32; i += 8)
    op[(size_t)(c0 + ty + i) * R + (r0 + tx)] = tile[tx][ty + i];
}

// ---------------------------------------------------------------------------
// QKV projection, GROUP of nb batches: embF f32 [nb*2048][1024] x WtT bf16
// [h][c][d] -> Q (pre-scaled by 0.125*log2e), K bf16 [(b*16+h)][s][64],
// V transposed -> Vt [(b*16+h)][dv][s].
// 1D grid nwg = 24*MB_CNT, XCD-chunked swizzle, m-major block order.
// A: f32 regs prefetched ONE K-STEP AHEAD (loads issued under MFMA; cvtpk +
// ds_write at next iter top) into padded As[128][40].
// B: global_load_lds width=16 into linear Bs[128][32].
// ---------------------------------------------------------------------------
__global__ __launch_bounds__(256)
void qkv_kernel(const float* __restrict__ embF,
                const unsigned short* __restrict__ WqT,
                const unsigned short* __restrict__ WkT,
                const unsigned short* __restrict__ WvT,
                unsigned short* __restrict__ QG,
                unsigned short* __restrict__ KG,
                unsigned short* __restrict__ VtG) {
  const int nwg = gridDim.x;                       // 24 * MB_CNT, %8 == 0
  const int wg = blockIdx.x;
  const int swz = (wg & 7) * (nwg >> 3) + (wg >> 3);
  const int mb = swz / 24;                         // emb panel index
  const int rem = swz - mb * 24;
  const int t = rem >> 3;                          // 0=Q, 1=K, 2=V
  const int m0 = mb * 128;
  const int n0 = (rem & 7) * 128;
  const int b = m0 >> 11;                          // local batch
  const int sloc = m0 & 2047;
  const unsigned short* Wt =
      (t == 0 ? WqT : (t == 1 ? WkT : WvT)) + (size_t)(n0 >> 6) * 64 * 1024;

  __shared__ __align__(16) unsigned short As[128][40];   // [m][k], +8 pad
  __shared__ __align__(16) unsigned short Bs[128 * 32];  // [n][k] linear

  const int tid = threadIdx.x;
  const int lane = tid & 63, w = tid >> 6;
  const int q4 = lane >> 4, l16 = lane & 15;
  const int lr = lane >> 2, lc = (lane & 3) * 8;     // B staging row/col-in-BK
  const int arow = tid >> 1, acol = (tid & 1) * 16;  // A staging

  f32x4 acc[4][4] = {};

  const float* aptr = &embF[(size_t)(m0 + arow) * 1024 + acol];
  const unsigned short* gb0 = &Wt[(size_t)(w * 32 + lr) * 1024 + lc];
  const unsigned short* gb1 = gb0 + 16 * 1024;
  char* lb0 = (char*)Bs + w * 2048;

  // prologue: A-regs for k0 = 0
  float4 v0 = *(const float4*)&aptr[0];
  float4 v1 = *(const float4*)&aptr[4];
  float4 v2 = *(const float4*)&aptr[8];
  float4 v3 = *(const float4*)&aptr[12];

  for (int k0 = 0; k0 < 1024; k0 += 32) {
    __syncthreads();                 // prev tile's ds_reads complete
    {  // convert prefetched A regs -> LDS (vmcnt wait landed ~1 iter after issue)
      u32x4 p0, p1;
      p0[0] = cvtpk(v0.x, v0.y); p0[1] = cvtpk(v0.z, v0.w);
      p0[2] = cvtpk(v1.x, v1.y); p0[3] = cvtpk(v1.z, v1.w);
      p1[0] = cvtpk(v2.x, v2.y); p1[1] = cvtpk(v2.z, v2.w);
      p1[2] = cvtpk(v3.x, v3.y); p1[3] = cvtpk(v3.z, v3.w);
      *(u32x4*)&As[arow][acol]     = p0;
      *(u32x4*)&As[arow][acol + 8] = p1;
    }
    gl16(gb0 + k0, lb0);             // async B staging
    gl16(gb1 + k0, lb0 + 1024);
    __syncthreads();                 // drains vmcnt + lgkm: tiles visible

    if (k0 + 32 < 1024) {            // prefetch NEXT A f32; hides under MFMA
      v0 = *(const float4*)&aptr[k0 + 32];
      v1 = *(const float4*)&aptr[k0 + 36];
      v2 = *(const float4*)&aptr[k0 + 40];
      v3 = *(const float4*)&aptr[k0 + 44];
    }

    bf16x8 af[4], bfr[4];
    if (t == 2) {
      // V^T = mfma(B, A): A-operand from Bs (linear), B-operand from As (padded)
#pragma unroll
      for (int ms = 0; ms < 4; ++ms)
        af[ms] = *(const bf16x8*)&Bs[((w >> 1) * 64 + ms * 16 + l16) * 32 + q4 * 8];
#pragma unroll
      for (int js = 0; js < 4; ++js)
        bfr[js] = *(const bf16x8*)&As[(w & 1) * 64 + js * 16 + l16][q4 * 8];
    } else {
#pragma unroll
      for (int ms = 0; ms < 4; ++ms)
        af[ms] = *(const bf16x8*)&As[(w >> 1) * 64 + ms * 16 + l16][q4 * 8];
#pragma unroll
      for (int js = 0; js < 4; ++js)
        bfr[js] = *(const bf16x8*)&Bs[((w & 1) * 64 + js * 16 + l16) * 32 + q4 * 8];
    }
    __builtin_amdgcn_s_setprio(1);
#pragma unroll
    for (int ms = 0; ms < 4; ++ms)
#pragma unroll
      for (int js = 0; js < 4; ++js)
        acc[ms][js] = MFMA16(af[ms], bfr[js], acc[ms][js]);
    __builtin_amdgcn_s_setprio(0);
  }

  if (t < 2) {
    unsigned short* outp = (t == 0) ? QG : KG;
    const float osc = (t == 0) ? (0.125f * LOG2E) : 1.0f;  // fold softmax scale into Q
    const int h = (n0 >> 6) + (w & 1);
    const size_t hb = (size_t)(b * 16 + h) * 2048;
#pragma unroll
    for (int ms = 0; ms < 4; ++ms)
#pragma unroll
      for (int js = 0; js < 4; ++js) {
        const int c = js * 16 + l16;
#pragma unroll
        for (int r = 0; r < 4; ++r) {
          const int s = sloc + (w >> 1) * 64 + ms * 16 + q4 * 4 + r;
          outp[(hb + s) * 64 + c] = f2bf(acc[ms][js][r] * osc);
        }
      }
  } else {
    const int h = (n0 >> 6) + (w >> 1);
    const size_t hb = (size_t)(b * 16 + h) * 64;
#pragma unroll
    for (int ms = 0; ms < 4; ++ms)
#pragma unroll
      for (int js = 0; js < 4; ++js) {
        const int s = sloc + (w & 1) * 64 + js * 16 + l16;
#pragma unroll
        for (int r = 0; r < 4; ++r) {
          const int c = ms * 16 + q4 * 4 + r;
          VtG[(hb + c) * 2048 + s] = f2bf(acc[ms][js][r]);
        }
      }
  }
}

// ---------------------------------------------------------------------------
// Flash attention, causal. Grid (16*nb bh, 16 y), 512 thr (8 waves).
// Block owns ONE 128-row q-tile t (y->t CU-balancing swizzle); wave w owns
// rows q0+16w..+15. Iterations per block = 2t+2; each CU's 4 resident
// blocks sum to 68 iters. Swapped-operand S^T = mfma(K,Q); softmax row is
// lane-local (q=l16). Deferred l-sum: per-lane partial, epilogue reduce.
// ---------------------------------------------------------------------------
__global__ __launch_bounds__(512)
void flash_kernel(const unsigned short* __restrict__ QG,
                  const unsigned short* __restrict__ KG,
                  const unsigned short* __restrict__ VtG,
                  unsigned short* __restrict__ ObG) {
  const int bh = blockIdx.x;
  const int y = blockIdx.y;                 // 0..15
  const int k4 = y >> 2, y0 = y & 3;
  const int t = k4 + 4 * ((y0 + k4) & 3);   // CU-balancing bijective swizzle
  const int q0 = t * 128;
  const int tid = threadIdx.x;
  const int lane = tid & 63, w = tid >> 6;  // w in 0..7
  const int wp = w & 3;
  const int q4 = lane >> 4, l16 = lane & 15;
  const int qw = q0 + w * 16;               // wave's first q-row
  const int jlim = q0 + ((w >= 4) ? 64 : 0);  // last j-tile this wave computes
  const int jlimB = q0 + 64;                  // block's last j-tile

  const unsigned short* Qp = QG + ((size_t)bh * 2048 + qw) * 64;
  const unsigned short* Kp = KG + (size_t)bh * 2048 * 64;
  const unsigned short* Vp = VtG + (size_t)bh * 64 * 2048;

  // B-fragment of Q for S^T mfma: lane holds Q[q=l16][d=q4*8..+8] (pre-scaled)
  const bf16x8 qf0 = *(const bf16x8*)&Qp[(size_t)l16 * 64 + q4 * 8];
  const bf16x8 qf1 = *(const bf16x8*)&Qp[(size_t)l16 * 64 + 32 + q4 * 8];

  __shared__ __align__(16) unsigned short Ks[64][72];       // [s][d]
  __shared__ __align__(16) unsigned short Vs[64][72];       // [dv][s]
  __shared__ __align__(16) unsigned short Plds[8][16][72];  // per-wave P[q][k]

  f32x4 oacc[4] = {};  // O^T: oacc[js][r] = O[q=l16][dv=js*16+q4*4+r]
  float m_i = BIG_NEG, l_part = 0.f;  // l_part: this lane's 16-col partial

  // staging: 512 threads, one 16B K-slice + one 16B V-slice each
  const int sr = tid >> 3, sc = (tid & 7) * 8;
  u32x4 kreg = *(const u32x4*)&Kp[(size_t)sr * 64 + sc];
  u32x4 vreg = *(const u32x4*)&Vp[(size_t)sr * 2048 + sc];

  for (int j0 = 0; j0 <= jlimB; j0 += 64) {
    *(u32x4*)&Ks[sr][sc] = kreg;
    *(u32x4*)&Vs[sr][sc] = vreg;
    __syncthreads();

    // prefetch next tile into regs; overlaps with the compute below (T14)
    if (j0 + 64 <= jlimB) {
      const int jn = j0 + 64;
      kreg = *(const u32x4*)&Kp[(size_t)(jn + sr) * 64 + sc];
      vreg = *(const u32x4*)&Vp[(size_t)sr * 2048 + jn + sc];
    }

    if (j0 <= jlim) {  // wave-uniform: this wave still has causal work
      // S^T tile: sacc[js][r] = S[q=l16][k = js*16 + q4*4 + r] (log2 domain)
      f32x4 sacc[4] = {};
      __builtin_amdgcn_s_setprio(1);
#pragma unroll
      for (int js = 0; js < 4; ++js) {
        const bf16x8 kf0 = *(const bf16x8*)&Ks[js * 16 + l16][q4 * 8];
        const bf16x8 kf1 = *(const bf16x8*)&Ks[js * 16 + l16][32 + q4 * 8];
        sacc[js] = MFMA16(kf0, qf0, sacc[js]);
        sacc[js] = MFMA16(kf1, qf1, sacc[js]);
      }
      __builtin_amdgcn_s_setprio(0);

      // causal mask (edge tile only) + in-lane max
      float mloc = BIG_NEG;
      if (j0 == jlim) {
        const int qrel = wp * 16 + l16;  // wave's row offset within this j-tile
#pragma unroll
        for (int js = 0; js < 4; ++js)
#pragma unroll
          for (int r = 0; r < 4; ++r) {
            const int krel = js * 16 + q4 * 4 + r;
            float v = sacc[js][r];
            if (krel > qrel) v = BIG_NEG;
            sacc[js][r] = v;
            mloc = fmaxf(mloc, v);
          }
      } else {
#pragma unroll
        for (int js = 0; js < 4; ++js)
#pragma unroll
          for (int r = 0; r < 4; ++r) mloc = fmaxf(mloc, sacc[js][r]);
      }
      // row max across the 4 q4-groups sharing q=l16
      mloc = fmaxf(mloc, __shfl_xor(mloc, 16, 64));
      mloc = fmaxf(mloc, __shfl_xor(mloc, 32, 64));

      // defer-max (T13): only rescale when the running max grew past THR
      if (__any(mloc > m_i + DEFER_THR)) {
        const float mnew = fmaxf(m_i, mloc);
        const float alpha = __builtin_amdgcn_exp2f(m_i - mnew);
        m_i = mnew;
        l_part *= alpha;
#pragma unroll
        for (int js = 0; js < 4; ++js)
#pragma unroll
          for (int r = 0; r < 4; ++r) oacc[js][r] *= alpha;
      }

#pragma unroll
      for (int js = 0; js < 4; ++js)
#pragma unroll
        for (int r = 0; r < 4; ++r) {
          const float p = __builtin_amdgcn_exp2f(sacc[js][r] - m_i);
          sacc[js][r] = p;
          l_part += p;  // sum reduce deferred to epilogue
        }

      // P store: row q=l16, 4 consecutive k per js -> one 8B write each
#pragma unroll
      for (int js = 0; js < 4; ++js) {
        u32x2 pk;
        pk[0] = cvtpk(sacc[js][0], sacc[js][1]);
        pk[1] = cvtpk(sacc[js][2], sacc[js][3]);
        *(u32x2*)&Plds[w][l16][js * 16 + q4 * 4] = pk;
      }

      asm volatile("" ::: "memory");

      // B-fragment of P^T: lane needs P[q=l16][k=q4*8..+8]
      const bf16x8 pf0 = *(const bf16x8*)&Plds[w][l16][q4 * 8];
      const bf16x8 pf1 = *(const bf16x8*)&Plds[w][l16][32 + q4 * 8];

      __builtin_amdgcn_s_setprio(1);
#pragma unroll
      for (int js = 0; js < 4; ++js) {
        const bf16x8 vf0 = *(const bf16x8*)&Vs[js * 16 + l16][q4 * 8];
        const bf16x8 vf1 = *(const bf16x8*)&Vs[js * 16 + l16][32 + q4 * 8];
        oacc[js] = MFMA16(vf0, pf0, oacc[js]);
        oacc[js] = MFMA16(vf1, pf1, oacc[js]);
      }
      __builtin_amdgcn_s_setprio(0);
    }
    __syncthreads();  // all LDS reads done before next iter's staging writes
  }

  // epilogue: reduce deferred l across the 4 q4-groups, then write O.
  float l_i = l_part;
  l_i += __shfl_xor(l_i, 16, 64);
  l_i += __shfl_xor(l_i, 32, 64);

  // concat-head layout ObG[b][s][h*64+dv]; 4 consecutive dv per 8B store
  const int b = bh >> 4, h = bh & 15;
  const int q = qw + l16;
  const float rl = 1.0f / l_i;
  unsigned short* orow = ObG + ((size_t)b * 2048 + q) * 1024 + h * 64;
#pragma unroll
  for (int js = 0; js < 4; ++js) {
    u32x2 ok;
    ok[0] = cvtpk(oacc[js][0] * rl, oacc[js][1] * rl);
    ok[1] = cvtpk(oacc[js][2] * rl, oacc[js][3] * rl);
    *(u32x2*)&orow[js * 16 + q4 * 4] = ok;
  }
}

// ---------------------------------------------------------------------------
// Output projection, GROUP: ObG bf16 [nb*2048][1024] x WoT bf16 [n][d]
// + bo(f32) -> outG f32 [nb*2048][1024].
// 1D grid nwg = 8*MB_CNT, XCD-chunked swizzle, m-major. gl16 staging.
// ---------------------------------------------------------------------------
__global__ __launch_bounds__(256)
void oproj_kernel(const unsigned short* __restrict__ ObG,
                  const unsigned short* __restrict__ WoT,
                  const float* __restrict__ bo,
                  float* __restrict__ outG) {
  const int nwg = gridDim.x;                       // 8 * MB_CNT, %8 == 0
  const int wg = blockIdx.x;
  const int swz = (wg & 7) * (nwg >> 3) + (wg >> 3);
  const int m0 = (swz >> 3) * 128;
  const int n0 = (swz & 7) * 128;

  __shared__ __align__(16) unsigned short As[128 * 32];
  __shared__ __align__(16) unsigned short Bs[128 * 32];

  const int tid = threadIdx.x;
  const int lane = tid & 63, w = tid >> 6;
  const int q4 = lane >> 4, l16 = lane & 15;
  const int lr = lane >> 2, lc = (lane & 3) * 8;

  f32x4 acc[4][4] = {};

  const unsigned short* ga0 = &ObG[(size_t)(m0 + w * 32 + lr) * 1024 + lc];
  const unsigned short* ga1 = ga0 + 16 * 1024;
  const unsigned short* gb0 = &WoT[(size_t)(n0 + w * 32 + lr) * 1024 + lc];
  const unsigned short* gb1 = gb0 + 16 * 1024;
  char* la0 = (char*)As + w * 2048;
  char* lb0 = (char*)Bs + w * 2048;

  for (int k0 = 0; k0 < 1024; k0 += 32) {
    __syncthreads();
    gl16(ga0 + k0, la0);
    gl16(ga1 + k0, la0 + 1024);
    gl16(gb0 + k0, lb0);
    gl16(gb1 + k0, lb0 + 1024);
    __syncthreads();

    bf16x8 af[4], bfr[4];
#pragma unroll
    for (int ms = 0; ms < 4; ++ms)
      af[ms] = *(const bf16x8*)&As[((w >> 1) * 64 + ms * 16 + l16) * 32 + q4 * 8];
#pragma unroll
    for (int js = 0; js < 4; ++js)
      bfr[js] = *(const bf16x8*)&Bs[((w & 1) * 64 + js * 16 + l16) * 32 + q4 * 8];
    __builtin_amdgcn_s_setprio(1);
#pragma unroll
    for (int ms = 0; ms < 4; ++ms)
#pragma unroll
      for (int js = 0; js < 4; ++js)
        acc[ms][js] = MFMA16(af[ms], bfr[js], acc[ms][js]);
    __builtin_amdgcn_s_setprio(0);
  }

#pragma unroll
  for (int js = 0; js < 4; ++js) {
    const int col = n0 + (w & 1) * 64 + js * 16 + l16;
    const float bias = bo[col];
#pragma unroll
    for (int ms = 0; ms < 4; ++ms)
#pragma unroll
      for (int r = 0; r < 4; ++r) {
        const int row = m0 + (w >> 1) * 64 + ms * 16 + q4 * 4 + r;
        outG[(size_t)row * 1024 + col] = acc[ms][js][r] + bias;  // f32 store
      }
  }
}

// ---------------------------------------------------------------------------
extern "C" void kernel_launch(void* const* d_in, const int* in_sizes, int n_in,
                              void* d_out, int out_size, void* d_ws, size_t ws_size,
                              hipStream_t stream) {
  const float* emb = (const float*)d_in[0];   // [4][2048][1024] f32
  const float* Wq  = (const float*)d_in[1];   // [16][1024][64]  f32
  const float* Wk  = (const float*)d_in[2];
  const float* Wv  = (const float*)d_in[3];
  const float* Wo  = (const float*)d_in[4];   // [1024][1024]    f32
  const float* bo  = (const float*)d_in[5];   // [1024]          f32
  float* out = (float*)d_out;                 // [4][2048][1024] f32

  char* ws = (char*)d_ws;
  const size_t MB = 1024 * 1024;

  // group size: nb batches per pipeline pass. ws need = 8 + 16*nb MB.
  const int nb = (ws_size >= 72 * MB) ? 4 : (ws_size >= 40 * MB) ? 2 : 1;

  unsigned short* WqT = (unsigned short*)(ws + 0 * MB);              // 2 MB [h][c][d]
  unsigned short* WkT = (unsigned short*)(ws + 2 * MB);              // 2 MB
  unsigned short* WvT = (unsigned short*)(ws + 4 * MB);              // 2 MB
  unsigned short* WoT = (unsigned short*)(ws + 6 * MB);              // 2 MB [n][d]
  unsigned short* QG  = (unsigned short*)(ws + 8 * MB);              // 4*nb MB
  unsigned short* KG  = (unsigned short*)(ws + (8 + 4 * nb) * MB);   // 4*nb MB
  unsigned short* VtG = (unsigned short*)(ws + (8 + 8 * nb) * MB);   // 4*nb MB
  unsigned short* ObG = (unsigned short*)(ws + (8 + 12 * nb) * MB);  // 4*nb MB

  const dim3 tb(32, 8, 1);
  wtrans_kernel<<<dim3(2, 32, 16), tb, 0, stream>>>(Wq, WqT, 1024, 64);
  wtrans_kernel<<<dim3(2, 32, 16), tb, 0, stream>>>(Wk, WkT, 1024, 64);
  wtrans_kernel<<<dim3(2, 32, 16), tb, 0, stream>>>(Wv, WvT, 1024, 64);
  wtrans_kernel<<<dim3(32, 32, 1), tb, 0, stream>>>(Wo, WoT, 1024, 1024);

  for (int g = 0; g < 4; g += nb) {
    const float* embG = emb + (size_t)g * 2048 * 1024;
    float* outG = out + (size_t)g * 2048 * 1024;
    qkv_kernel<<<dim3(24 * 16 * nb), 256, 0, stream>>>(embG, WqT, WkT, WvT, QG, KG, VtG);
    flash_kernel<<<dim3(16 * nb, 16), 512, 0, stream>>>(QG, KG, VtG, ObG);
    oproj_kernel<<<dim3(8 * 16 * nb), 256, 0, stream>>>(ObG, WoT, bo, outG);
  }
}

// Round 9
// 265.499 us; speedup vs baseline: 1.1998x; 1.1998x over previous
//
#include <hip/hip_runtime.h>
#include <hip/hip_bf16.h>

// B=4, S=2048, D=1024, H=16, DK=DV=64. Inputs f32, output f32 (confirmed r8).
// MFMA math bf16 with f32 accum. Round 18:
//  - REVERT to r15 pipeline (best measured: 280.4 us): embconv + gl16-qkv +
//    128-row-tile flash + gl16-oproj. (r16/r17 fused-convert regressed.)
//  - ONE change: flash LDS XOR-swizzle. Ks/Vs/Plds move to linear 64-short
//    rows with 16B-slot index XOR (row&7) on write AND read. Kills the
//    constant 11.9M SQ_LDS_BANK_CONFLICT (~23% of CU-cycles). All swizzled
//    offsets are loop-invariant per thread (row&7 == l16&7): zero VALU cost.

typedef __attribute__((ext_vector_type(8))) short bf16x8;
typedef __attribute__((ext_vector_type(4))) float f32x4;
typedef __attribute__((ext_vector_type(4))) unsigned int u32x4;
typedef __attribute__((ext_vector_type(2))) unsigned int u32x2;

#define MFMA16(a, b, c) __builtin_amdgcn_mfma_f32_16x16x32_bf16((a), (b), (c), 0, 0, 0)

#define LOG2E 1.44269504088896340736f
#define BIG_NEG (-3.0e38f)
#define DEFER_THR 10.0f  // log2-domain; P bounded by 2^10 when rescale skipped

__device__ __forceinline__ unsigned short f2bf(float f) {
  union { float f; unsigned int i; } x; x.f = f;
  unsigned int lsb = (x.i >> 16) & 1;
  x.i += 0x7fffu + lsb;  // RNE (finite inputs only)
  return (unsigned short)(x.i >> 16);
}

__device__ __forceinline__ unsigned int cvtpk(float lo, float hi) {
  unsigned int r;
  asm("v_cvt_pk_bf16_f32 %0, %1, %2" : "=v"(r) : "v"(lo), "v"(hi));
  return r;
}

// global -> LDS direct DMA, 16B per lane. lds dest must be wave-uniform base;
// HW writes base + lane*16. Global src is per-lane.
__device__ __forceinline__ void gl16(const unsigned short* g, void* l) {
  __builtin_amdgcn_global_load_lds(
      (const __attribute__((address_space(1))) unsigned int*)g,
      (__attribute__((address_space(3))) unsigned int*)l, 16, 0, 0);
}

// ---------------------------------------------------------------------------
// Batched transpose + downconvert: in f32 [batch][R][C] -> out bf16 [batch][C][R]
// ---------------------------------------------------------------------------
__global__ void wtrans_kernel(const float* __restrict__ in,
                              unsigned short* __restrict__ out, int R, int C) {
  __shared__ unsigned short tile[32][33];
  const int bz = blockIdx.z;
  const int c0 = blockIdx.x * 32, r0 = blockIdx.y * 32;
  const float* ip = in + (size_t)bz * R * C;
  unsigned short* op = out + (size_t)bz * R * C;
  const int tx = threadIdx.x, ty = threadIdx.y;  // (32, 8)
#pragma unroll
  for (int i = 0; i < 32; i += 8)
    tile[ty + i][tx] = f2bf(ip[(size_t)(r0 + ty + i) * C + (c0 + tx)]);
  __syncthreads();
#pragma unroll
  for (int i = 0; i < 32; i += 8)
    op[(size_t)(c0 + ty + i) * R + (r0 + tx)] = tile[tx][ty + i];
}

// ---------------------------------------------------------------------------
// f32 -> bf16 bulk convert (emb). Grid covers exactly n/8 threads.
// ---------------------------------------------------------------------------
__global__ __launch_bounds__(256)
void embconv_kernel(const float* __restrict__ in, unsigned short* __restrict__ out) {
  const int i = blockIdx.x * 256 + threadIdx.x;
  const float4 a = ((const float4*)in)[2 * i];
  const float4 b = ((const float4*)in)[2 * i + 1];
  union { unsigned short u[8]; u32x4 v; } p;
  p.u[0] = f2bf(a.x); p.u[1] = f2bf(a.y); p.u[2] = f2bf(a.z); p.u[3] = f2bf(a.w);
  p.u[4] = f2bf(b.x); p.u[5] = f2bf(b.y); p.u[6] = f2bf(b.z); p.u[7] = f2bf(b.w);
  ((u32x4*)out)[i] = p.v;
}

// ---------------------------------------------------------------------------
// QKV projection, GROUP of nb batches: embB bf16 [nb*2048][1024] x WtT bf16
// [h][c][d] -> Q (pre-scaled by 0.125*log2e), K bf16 [(b*16+h)][s][64],
// V transposed -> Vt [(b*16+h)][dv][s].
// 1D grid nwg = 24*MB_CNT, XCD-chunked swizzle, m-major block order.
// Staging: global_load_lds width=16 into linear As/Bs [128][32].
// ---------------------------------------------------------------------------
__global__ __launch_bounds__(256)
void qkv_kernel(const unsigned short* __restrict__ embB,
                const unsigned short* __restrict__ WqT,
                const unsigned short* __restrict__ WkT,
                const unsigned short* __restrict__ WvT,
                unsigned short* __restrict__ QG,
                unsigned short* __restrict__ KG,
                unsigned short* __restrict__ VtG) {
  const int nwg = gridDim.x;                       // 24 * MB_CNT, %8 == 0
  const int wg = blockIdx.x;
  const int swz = (wg & 7) * (nwg >> 3) + (wg >> 3);
  const int mb = swz / 24;                         // embB panel index
  const int rem = swz - mb * 24;
  const int t = rem >> 3;                          // 0=Q, 1=K, 2=V
  const int m0 = mb * 128;
  const int n0 = (rem & 7) * 128;
  const int b = m0 >> 11;                          // local batch
  const int sloc = m0 & 2047;
  const unsigned short* Wt =
      (t == 0 ? WqT : (t == 1 ? WkT : WvT)) + (size_t)(n0 >> 6) * 64 * 1024;

  __shared__ __align__(16) unsigned short As[128 * 32];  // [m][k] linear
  __shared__ __align__(16) unsigned short Bs[128 * 32];  // [n][k] linear

  const int tid = threadIdx.x;
  const int lane = tid & 63, w = tid >> 6;
  const int q4 = lane >> 4, l16 = lane & 15;
  const int lr = lane >> 2, lc = (lane & 3) * 8;   // staging: row/col-in-BK

  f32x4 acc[4][4] = {};

  // wave w stages rows [w*32, w*32+32) of each 128x32 tile (2 x 1KB DMAs)
  const unsigned short* ga0 = &embB[(size_t)(m0 + w * 32 + lr) * 1024 + lc];
  const unsigned short* ga1 = ga0 + 16 * 1024;
  const unsigned short* gb0 = &Wt[(size_t)(w * 32 + lr) * 1024 + lc];
  const unsigned short* gb1 = gb0 + 16 * 1024;
  char* la0 = (char*)As + w * 2048;
  char* lb0 = (char*)Bs + w * 2048;

  for (int k0 = 0; k0 < 1024; k0 += 32) {
    __syncthreads();                 // prev tile's ds_reads complete
    gl16(ga0 + k0, la0);
    gl16(ga1 + k0, la0 + 1024);
    gl16(gb0 + k0, lb0);
    gl16(gb1 + k0, lb0 + 1024);
    __syncthreads();                 // drains vmcnt: tiles visible

    // t==2: compute (W^T * emb^T) = V^T directly by swapping operand roles.
    const unsigned short* PA = (t == 2) ? Bs : As;
    const unsigned short* PB = (t == 2) ? As : Bs;

    bf16x8 af[4], bfr[4];
#pragma unroll
    for (int ms = 0; ms < 4; ++ms)
      af[ms] = *(const bf16x8*)&PA[((w >> 1) * 64 + ms * 16 + l16) * 32 + q4 * 8];
#pragma unroll
    for (int js = 0; js < 4; ++js)
      bfr[js] = *(const bf16x8*)&PB[((w & 1) * 64 + js * 16 + l16) * 32 + q4 * 8];
    __builtin_amdgcn_s_setprio(1);
#pragma unroll
    for (int ms = 0; ms < 4; ++ms)
#pragma unroll
      for (int js = 0; js < 4; ++js)
        acc[ms][js] = MFMA16(af[ms], bfr[js], acc[ms][js]);
    __builtin_amdgcn_s_setprio(0);
  }

  if (t < 2) {
    unsigned short* outp = (t == 0) ? QG : KG;
    const float osc = (t == 0) ? (0.125f * LOG2E) : 1.0f;  // fold softmax scale into Q
    const int h = (n0 >> 6) + (w & 1);
    const size_t hb = (size_t)(b * 16 + h) * 2048;
#pragma unroll
    for (int ms = 0; ms < 4; ++ms)
#pragma unroll
      for (int js = 0; js < 4; ++js) {
        const int c = js * 16 + l16;
#pragma unroll
        for (int r = 0; r < 4; ++r) {
          const int s = sloc + (w >> 1) * 64 + ms * 16 + q4 * 4 + r;
          outp[(hb + s) * 64 + c] = f2bf(acc[ms][js][r] * osc);
        }
      }
  } else {
    const int h = (n0 >> 6) + (w >> 1);
    const size_t hb = (size_t)(b * 16 + h) * 64;
#pragma unroll
    for (int ms = 0; ms < 4; ++ms)
#pragma unroll
      for (int js = 0; js < 4; ++js) {
        const int s = sloc + (w & 1) * 64 + js * 16 + l16;
#pragma unroll
        for (int r = 0; r < 4; ++r) {
          const int c = ms * 16 + q4 * 4 + r;
          VtG[(hb + c) * 2048 + s] = f2bf(acc[ms][js][r]);
        }
      }
  }
}

// ---------------------------------------------------------------------------
// Flash attention, causal. Grid (16*nb bh, 16 y), 512 thr (8 waves).
// Block owns ONE 128-row q-tile t (y->t CU-balancing swizzle); wave w owns
// rows q0+16w..+15. Iterations per block = 2t+2; each CU's 4 resident
// blocks sum to 68 iters. Swapped-operand S^T = mfma(K,Q); softmax row is
// lane-local (q=l16). Deferred l-sum: per-lane partial, epilogue reduce.
// LDS XOR-swizzle: Ks/Vs/Plds linear 64-short rows; 16B-slot ^= (row&7) on
// write and read -> conflict-free (slots cover all 32 banks). Offsets are
// loop-invariant per thread (row&7 == l16&7).
// ---------------------------------------------------------------------------
__global__ __launch_bounds__(512)
void flash_kernel(const unsigned short* __restrict__ QG,
                  const unsigned short* __restrict__ KG,
                  const unsigned short* __restrict__ VtG,
                  unsigned short* __restrict__ ObG) {
  const int bh = blockIdx.x;
  const int y = blockIdx.y;                 // 0..15
  const int k4 = y >> 2, y0 = y & 3;
  const int t = k4 + 4 * ((y0 + k4) & 3);   // CU-balancing bijective swizzle
  const int q0 = t * 128;
  const int tid = threadIdx.x;
  const int lane = tid & 63, w = tid >> 6;  // w in 0..7
  const int wp = w & 3;
  const int q4 = lane >> 4, l16 = lane & 15;
  const int qw = q0 + w * 16;               // wave's first q-row
  const int jlim = q0 + ((w >= 4) ? 64 : 0);  // last j-tile this wave computes
  const int jlimB = q0 + 64;                  // block's last j-tile

  const unsigned short* Qp = QG + ((size_t)bh * 2048 + qw) * 64;
  const unsigned short* Kp = KG + (size_t)bh * 2048 * 64;
  const unsigned short* Vp = VtG + (size_t)bh * 64 * 2048;

  // B-fragment of Q for S^T mfma: lane holds Q[q=l16][d=q4*8..+8] (pre-scaled)
  const bf16x8 qf0 = *(const bf16x8*)&Qp[(size_t)l16 * 64 + q4 * 8];
  const bf16x8 qf1 = *(const bf16x8*)&Qp[(size_t)l16 * 64 + 32 + q4 * 8];

  __shared__ __align__(16) unsigned short Ks[64 * 64];       // [s][d] swizzled
  __shared__ __align__(16) unsigned short Vs[64 * 64];       // [dv][s] swizzled
  __shared__ __align__(16) unsigned short Plds[8 * 16 * 64]; // per-wave P[q][k] swz

  f32x4 oacc[4] = {};  // O^T: oacc[js][r] = O[q=l16][dv=js*16+q4*4+r]
  float m_i = BIG_NEG, l_part = 0.f;  // l_part: this lane's 16-col partial

  // staging: 512 threads, one 16B K-slice + one 16B V-slice each.
  // LDS dest: row sr, slot (tid&7)^(sr&7)  (XOR swizzle, loop-invariant)
  const int sr = tid >> 3, sc = (tid & 7) * 8;
  const int sdst = sr * 64 + (((tid & 7) ^ (sr & 7)) * 8);
  u32x4 kreg = *(const u32x4*)&Kp[(size_t)sr * 64 + sc];
  u32x4 vreg = *(const u32x4*)&Vp[(size_t)sr * 2048 + sc];

  // loop-invariant swizzled read offsets (row&7 == l16&7 for all fragment rows)
  const int x7 = l16 & 7;
  const int ks0 = (q4 ^ x7) * 8;            // K/V slot for first 32 shorts
  const int ks1 = ((4 + q4) ^ x7) * 8;      // ... second 32 shorts
  const int prow = (w * 16 + l16) * 64;     // this lane's P row base
  // P write slots per js: 8B at slot js*2+(q4>>1), offset (q4&1)*4 shorts
  // P read: same slots as K (ks0/ks1 pattern)

  for (int j0 = 0; j0 <= jlimB; j0 += 64) {
    *(u32x4*)&Ks[sdst] = kreg;
    *(u32x4*)&Vs[sdst] = vreg;
    __syncthreads();

    // prefetch next tile into regs; overlaps with the compute below (T14)
    if (j0 + 64 <= jlimB) {
      const int jn = j0 + 64;
      kreg = *(const u32x4*)&Kp[(size_t)(jn + sr) * 64 + sc];
      vreg = *(const u32x4*)&Vp[(size_t)sr * 2048 + jn + sc];
    }

    if (j0 <= jlim) {  // wave-uniform: this wave still has causal work
      // S^T tile: sacc[js][r] = S[q=l16][k = js*16 + q4*4 + r] (log2 domain)
      f32x4 sacc[4] = {};
      __builtin_amdgcn_s_setprio(1);
#pragma unroll
      for (int js = 0; js < 4; ++js) {
        const int krow = (js * 16 + l16) * 64;
        const bf16x8 kf0 = *(const bf16x8*)&Ks[krow + ks0];
        const bf16x8 kf1 = *(const bf16x8*)&Ks[krow + ks1];
        sacc[js] = MFMA16(kf0, qf0, sacc[js]);
        sacc[js] = MFMA16(kf1, qf1, sacc[js]);
      }
      __builtin_amdgcn_s_setprio(0);

      // causal mask (edge tile only) + in-lane max
      float mloc = BIG_NEG;
      if (j0 == jlim) {
        const int qrel = wp * 16 + l16;  // wave's row offset within this j-tile
#pragma unroll
        for (int js = 0; js < 4; ++js)
#pragma unroll
          for (int r = 0; r < 4; ++r) {
            const int krel = js * 16 + q4 * 4 + r;
            float v = sacc[js][r];
            if (krel > qrel) v = BIG_NEG;
            sacc[js][r] = v;
            mloc = fmaxf(mloc, v);
          }
      } else {
#pragma unroll
        for (int js = 0; js < 4; ++js)
#pragma unroll
          for (int r = 0; r < 4; ++r) mloc = fmaxf(mloc, sacc[js][r]);
      }
      // row max across the 4 q4-groups sharing q=l16
      mloc = fmaxf(mloc, __shfl_xor(mloc, 16, 64));
      mloc = fmaxf(mloc, __shfl_xor(mloc, 32, 64));

      // defer-max (T13): only rescale when the running max grew past THR
      if (__any(mloc > m_i + DEFER_THR)) {
        const float mnew = fmaxf(m_i, mloc);
        const float alpha = __builtin_amdgcn_exp2f(m_i - mnew);
        m_i = mnew;
        l_part *= alpha;
#pragma unroll
        for (int js = 0; js < 4; ++js)
#pragma unroll
          for (int r = 0; r < 4; ++r) oacc[js][r] *= alpha;
      }

#pragma unroll
      for (int js = 0; js < 4; ++js)
#pragma unroll
        for (int r = 0; r < 4; ++r) {
          const float p = __builtin_amdgcn_exp2f(sacc[js][r] - m_i);
          sacc[js][r] = p;
          l_part += p;  // sum reduce deferred to epilogue
        }

      // P store: row q=l16; 8B at swizzled slot js*2+(q4>>1) ^ x7
#pragma unroll
      for (int js = 0; js < 4; ++js) {
        u32x2 pk;
        pk[0] = cvtpk(sacc[js][0], sacc[js][1]);
        pk[1] = cvtpk(sacc[js][2], sacc[js][3]);
        const int pslot = (((js * 2 + (q4 >> 1)) ^ x7) * 8) + ((q4 & 1) * 4);
        *(u32x2*)&Plds[prow + pslot] = pk;
      }

      asm volatile("" ::: "memory");

      // B-fragment of P^T: lane needs P[q=l16][k=q4*8..+8] (swizzled slots)
      const int prd = (w * 16 + l16) * 64;
      const bf16x8 pf0 = *(const bf16x8*)&Plds[prd + ks0];
      const bf16x8 pf1 = *(const bf16x8*)&Plds[prd + ks1];

      __builtin_amdgcn_s_setprio(1);
#pragma unroll
      for (int js = 0; js < 4; ++js) {
        const int vrow = (js * 16 + l16) * 64;
        const bf16x8 vf0 = *(const bf16x8*)&Vs[vrow + ks0];
        const bf16x8 vf1 = *(const bf16x8*)&Vs[vrow + ks1];
        oacc[js] = MFMA16(vf0, pf0, oacc[js]);
        oacc[js] = MFMA16(vf1, pf1, oacc[js]);
      }
      __builtin_amdgcn_s_setprio(0);
    }
    __syncthreads();  // all LDS reads done before next iter's staging writes
  }

  // epilogue: reduce deferred l across the 4 q4-groups, then write O.
  float l_i = l_part;
  l_i += __shfl_xor(l_i, 16, 64);
  l_i += __shfl_xor(l_i, 32, 64);

  // concat-head layout ObG[b][s][h*64+dv]; 4 consecutive dv per 8B store
  const int b = bh >> 4, h = bh & 15;
  const int q = qw + l16;
  const float rl = 1.0f / l_i;
  unsigned short* orow = ObG + ((size_t)b * 2048 + q) * 1024 + h * 64;
#pragma unroll
  for (int js = 0; js < 4; ++js) {
    u32x2 ok;
    ok[0] = cvtpk(oacc[js][0] * rl, oacc[js][1] * rl);
    ok[1] = cvtpk(oacc[js][2] * rl, oacc[js][3] * rl);
    *(u32x2*)&orow[js * 16 + q4 * 4] = ok;
  }
}

// ---------------------------------------------------------------------------
// Output projection, GROUP: ObG bf16 [nb*2048][1024] x WoT bf16 [n][d]
// + bo(f32) -> outG f32 [nb*2048][1024].
// 1D grid nwg = 8*MB_CNT, XCD-chunked swizzle, m-major. gl16 staging.
// ---------------------------------------------------------------------------
__global__ __launch_bounds__(256)
void oproj_kernel(const unsigned short* __restrict__ ObG,
                  const unsigned short* __restrict__ WoT,
                  const float* __restrict__ bo,
                  float* __restrict__ outG) {
  const int nwg = gridDim.x;                       // 8 * MB_CNT, %8 == 0
  const int wg = blockIdx.x;
  const int swz = (wg & 7) * (nwg >> 3) + (wg >> 3);
  const int m0 = (swz >> 3) * 128;
  const int n0 = (swz & 7) * 128;

  __shared__ __align__(16) unsigned short As[128 * 32];
  __shared__ __align__(16) unsigned short Bs[128 * 32];

  const int tid = threadIdx.x;
  const int lane = tid & 63, w = tid >> 6;
  const int q4 = lane >> 4, l16 = lane & 15;
  const int lr = lane >> 2, lc = (lane & 3) * 8;

  f32x4 acc[4][4] = {};

  const unsigned short* ga0 = &ObG[(size_t)(m0 + w * 32 + lr) * 1024 + lc];
  const unsigned short* ga1 = ga0 + 16 * 1024;
  const unsigned short* gb0 = &WoT[(size_t)(n0 + w * 32 + lr) * 1024 + lc];
  const unsigned short* gb1 = gb0 + 16 * 1024;
  char* la0 = (char*)As + w * 2048;
  char* lb0 = (char*)Bs + w * 2048;

  for (int k0 = 0; k0 < 1024; k0 += 32) {
    __syncthreads();
    gl16(ga0 + k0, la0);
    gl16(ga1 + k0, la0 + 1024);
    gl16(gb0 + k0, lb0);
    gl16(gb1 + k0, lb0 + 1024);
    __syncthreads();

    bf16x8 af[4], bfr[4];
#pragma unroll
    for (int ms = 0; ms < 4; ++ms)
      af[ms] = *(const bf16x8*)&As[((w >> 1) * 64 + ms * 16 + l16) * 32 + q4 * 8];
#pragma unroll
    for (int js = 0; js < 4; ++js)
      bfr[js] = *(const bf16x8*)&Bs[((w & 1) * 64 + js * 16 + l16) * 32 + q4 * 8];
    __builtin_amdgcn_s_setprio(1);
#pragma unroll
    for (int ms = 0; ms < 4; ++ms)
#pragma unroll
      for (int js = 0; js < 4; ++js)
        acc[ms][js] = MFMA16(af[ms], bfr[js], acc[ms][js]);
    __builtin_amdgcn_s_setprio(0);
  }

#pragma unroll
  for (int js = 0; js < 4; ++js) {
    const int col = n0 + (w & 1) * 64 + js * 16 + l16;
    const float bias = bo[col];
#pragma unroll
    for (int ms = 0; ms < 4; ++ms)
#pragma unroll
      for (int r = 0; r < 4; ++r) {
        const int row = m0 + (w >> 1) * 64 + ms * 16 + q4 * 4 + r;
        outG[(size_t)row * 1024 + col] = acc[ms][js][r] + bias;  // f32 store
      }
  }
}

// ---------------------------------------------------------------------------
extern "C" void kernel_launch(void* const* d_in, const int* in_sizes, int n_in,
                              void* d_out, int out_size, void* d_ws, size_t ws_size,
                              hipStream_t stream) {
  const float* emb = (const float*)d_in[0];   // [4][2048][1024] f32
  const float* Wq  = (const float*)d_in[1];   // [16][1024][64]  f32
  const float* Wk  = (const float*)d_in[2];
  const float* Wv  = (const float*)d_in[3];
  const float* Wo  = (const float*)d_in[4];   // [1024][1024]    f32
  const float* bo  = (const float*)d_in[5];   // [1024]          f32
  float* out = (float*)d_out;                 // [4][2048][1024] f32

  char* ws = (char*)d_ws;
  const size_t MB = 1024 * 1024;

  // group size: nb batches per pipeline pass. ws need = 8 + 16*nb MB.
  const int nb = (ws_size >= 72 * MB) ? 4 : (ws_size >= 40 * MB) ? 2 : 1;

  unsigned short* WqT = (unsigned short*)(ws + 0 * MB);              // 2 MB [h][c][d]
  unsigned short* WkT = (unsigned short*)(ws + 2 * MB);              // 2 MB
  unsigned short* WvT = (unsigned short*)(ws + 4 * MB);              // 2 MB
  unsigned short* WoT = (unsigned short*)(ws + 6 * MB);              // 2 MB [n][d]
  unsigned short* QG  = (unsigned short*)(ws + 8 * MB);              // 4*nb MB
  unsigned short* KG  = (unsigned short*)(ws + (8 + 4 * nb) * MB);   // 4*nb MB
  unsigned short* VtG = (unsigned short*)(ws + (8 + 8 * nb) * MB);   // 4*nb MB
  unsigned short* ObG = (unsigned short*)(ws + (8 + 12 * nb) * MB);  // 4*nb MB

  const dim3 tb(32, 8, 1);
  wtrans_kernel<<<dim3(2, 32, 16), tb, 0, stream>>>(Wq, WqT, 1024, 64);
  wtrans_kernel<<<dim3(2, 32, 16), tb, 0, stream>>>(Wk, WkT, 1024, 64);
  wtrans_kernel<<<dim3(2, 32, 16), tb, 0, stream>>>(Wv, WvT, 1024, 64);
  wtrans_kernel<<<dim3(32, 32, 1), tb, 0, stream>>>(Wo, WoT, 1024, 1024);

  for (int g = 0; g < 4; g += nb) {
    const float* embG = emb + (size_t)g * 2048 * 1024;
    float* outG = out + (size_t)g * 2048 * 1024;
    // embB (bf16 emb) aliases ObG: dead before flash writes ObG, per group.
    unsigned short* embB = ObG;
    embconv_kernel<<<dim3(nb * 1024), 256, 0, stream>>>(embG, embB);
    qkv_kernel<<<dim3(24 * 16 * nb), 256, 0, stream>>>(embB, WqT, WkT, WvT, QG, KG, VtG);
    flash_kernel<<<dim3(16 * nb, 16), 512, 0, stream>>>(QG, KG, VtG, ObG);
    oproj_kernel<<<dim3(8 * 16 * nb), 256, 0, stream>>>(ObG, WoT, bo, outG);
  }
}

// Round 10
// 250.559 us; speedup vs baseline: 1.2713x; 1.0596x over previous
//
#include <hip/hip_runtime.h>
#include <hip/hip_bf16.h>

// B=4, S=2048, D=1024, H=16, DK=DV=64. Inputs f32, output f32 (confirmed r8).
// MFMA math bf16 with f32 accum. Round 19 (base: r18 = 265.5 us):
//  - qkv/oproj: BK=64 (halves barrier-drain windows 32->16) + pre-swizzled
//    gl16 source so the linear DMA yields an XOR-swizzled LDS (slot c^(r&7));
//    fragment reads use the same involution -> kills qkv's 6.3M bank
//    conflicts. Both-sides-or-neither per rule #21; offsets loop-invariant.
//  - flash: unchanged from r18 (swizzled, conflict-free).
//  - wtrans: Wq/Wk/Wv merged into one launch (8 -> 6 dispatches).

typedef __attribute__((ext_vector_type(8))) short bf16x8;
typedef __attribute__((ext_vector_type(4))) float f32x4;
typedef __attribute__((ext_vector_type(4))) unsigned int u32x4;
typedef __attribute__((ext_vector_type(2))) unsigned int u32x2;

#define MFMA16(a, b, c) __builtin_amdgcn_mfma_f32_16x16x32_bf16((a), (b), (c), 0, 0, 0)

#define LOG2E 1.44269504088896340736f
#define BIG_NEG (-3.0e38f)
#define DEFER_THR 10.0f  // log2-domain; P bounded by 2^10 when rescale skipped

__device__ __forceinline__ unsigned short f2bf(float f) {
  union { float f; unsigned int i; } x; x.f = f;
  unsigned int lsb = (x.i >> 16) & 1;
  x.i += 0x7fffu + lsb;  // RNE (finite inputs only)
  return (unsigned short)(x.i >> 16);
}

__device__ __forceinline__ unsigned int cvtpk(float lo, float hi) {
  unsigned int r;
  asm("v_cvt_pk_bf16_f32 %0, %1, %2" : "=v"(r) : "v"(lo), "v"(hi));
  return r;
}

// global -> LDS direct DMA, 16B per lane. lds dest must be wave-uniform base;
// HW writes base + lane*16. Global src is per-lane.
__device__ __forceinline__ void gl16(const unsigned short* g, void* l) {
  __builtin_amdgcn_global_load_lds(
      (const __attribute__((address_space(1))) unsigned int*)g,
      (__attribute__((address_space(3))) unsigned int*)l, 16, 0, 0);
}

// ---------------------------------------------------------------------------
// Transpose + downconvert for Wq/Wk/Wv in ONE launch: z = which*16 + head.
// in f32 [16][1024][64] -> out bf16 [16][64][1024]
// ---------------------------------------------------------------------------
__global__ void wtrans3_kernel(const float* __restrict__ Wq,
                               const float* __restrict__ Wk,
                               const float* __restrict__ Wv,
                               unsigned short* __restrict__ Oq,
                               unsigned short* __restrict__ Ok,
                               unsigned short* __restrict__ Ov) {
  __shared__ unsigned short tile[32][33];
  const int bz = blockIdx.z;              // 0..47
  const int which = bz >> 4, h = bz & 15;
  const float* ip = (which == 0 ? Wq : which == 1 ? Wk : Wv) + (size_t)h * 1024 * 64;
  unsigned short* op = (which == 0 ? Oq : which == 1 ? Ok : Ov) + (size_t)h * 1024 * 64;
  const int c0 = blockIdx.x * 32, r0 = blockIdx.y * 32;
  const int tx = threadIdx.x, ty = threadIdx.y;  // (32, 8)
#pragma unroll
  for (int i = 0; i < 32; i += 8)
    tile[ty + i][tx] = f2bf(ip[(size_t)(r0 + ty + i) * 64 + (c0 + tx)]);
  __syncthreads();
#pragma unroll
  for (int i = 0; i < 32; i += 8)
    op[(size_t)(c0 + ty + i) * 1024 + (r0 + tx)] = tile[tx][ty + i];
}

// Wo transpose: in f32 [1024][1024] -> out bf16 [1024][1024]^T
__global__ void wtrans_kernel(const float* __restrict__ in,
                              unsigned short* __restrict__ out, int R, int C) {
  __shared__ unsigned short tile[32][33];
  const int c0 = blockIdx.x * 32, r0 = blockIdx.y * 32;
  const int tx = threadIdx.x, ty = threadIdx.y;  // (32, 8)
#pragma unroll
  for (int i = 0; i < 32; i += 8)
    tile[ty + i][tx] = f2bf(in[(size_t)(r0 + ty + i) * C + (c0 + tx)]);
  __syncthreads();
#pragma unroll
  for (int i = 0; i < 32; i += 8)
    out[(size_t)(c0 + ty + i) * R + (r0 + tx)] = tile[tx][ty + i];
}

// ---------------------------------------------------------------------------
// f32 -> bf16 bulk convert (emb). Grid covers exactly n/8 threads.
// ---------------------------------------------------------------------------
__global__ __launch_bounds__(256)
void embconv_kernel(const float* __restrict__ in, unsigned short* __restrict__ out) {
  const int i = blockIdx.x * 256 + threadIdx.x;
  const float4 a = ((const float4*)in)[2 * i];
  const float4 b = ((const float4*)in)[2 * i + 1];
  union { unsigned short u[8]; u32x4 v; } p;
  p.u[0] = f2bf(a.x); p.u[1] = f2bf(a.y); p.u[2] = f2bf(a.z); p.u[3] = f2bf(a.w);
  p.u[4] = f2bf(b.x); p.u[5] = f2bf(b.y); p.u[6] = f2bf(b.z); p.u[7] = f2bf(b.w);
  ((u32x4*)out)[i] = p.v;
}

// ---------------------------------------------------------------------------
// QKV projection, GROUP of nb batches: embB bf16 [nb*2048][1024] x WtT bf16
// [h][c][d] -> Q (pre-scaled by 0.125*log2e), K bf16 [(b*16+h)][s][64],
// V transposed -> Vt [(b*16+h)][dv][s].
// 1D grid nwg = 24*MB_CNT, XCD-chunked swizzle, m-major block order.
// BK=64. Staging: gl16 with PRE-SWIZZLED global source (lane l loads col
// chunk (l&7)^((l>>3)&7)) -> LDS holds chunk c at slot c^(row&7). Fragment
// reads use slot (kk*4+q4)^(l16&7): conflict-free, loop-invariant.
// ---------------------------------------------------------------------------
__global__ __launch_bounds__(256)
void qkv_kernel(const unsigned short* __restrict__ embB,
                const unsigned short* __restrict__ WqT,
                const unsigned short* __restrict__ WkT,
                const unsigned short* __restrict__ WvT,
                unsigned short* __restrict__ QG,
                unsigned short* __restrict__ KG,
                unsigned short* __restrict__ VtG) {
  const int nwg = gridDim.x;                       // 24 * MB_CNT, %8 == 0
  const int wg = blockIdx.x;
  const int swz = (wg & 7) * (nwg >> 3) + (wg >> 3);
  const int mb = swz / 24;                         // embB panel index
  const int rem = swz - mb * 24;
  const int t = rem >> 3;                          // 0=Q, 1=K, 2=V
  const int m0 = mb * 128;
  const int n0 = (rem & 7) * 128;
  const int b = m0 >> 11;                          // local batch
  const int sloc = m0 & 2047;
  const unsigned short* Wt =
      (t == 0 ? WqT : (t == 1 ? WkT : WvT)) + (size_t)(n0 >> 6) * 64 * 1024;

  __shared__ __align__(16) unsigned short As[128 * 64];  // [m][64] swizzled slots
  __shared__ __align__(16) unsigned short Bs[128 * 64];  // [n][64] swizzled slots

  const int tid = threadIdx.x;
  const int lane = tid & 63, w = tid >> 6;
  const int q4 = lane >> 4, l16 = lane & 15;
  const int x7 = l16 & 7;

  f32x4 acc[4][4] = {};

  // staging: wave w covers rows [w*32, w*32+32) of both 128x64 tiles.
  // gl16 i stages rows w*32+i*8+(lane>>3); lane loads pre-swizzled col chunk.
  const int grow = w * 32 + (lane >> 3);
  const int gcol = (((lane & 7) ^ ((lane >> 3) & 7)) * 8);
  const unsigned short* gaB = &embB[(size_t)(m0 + grow) * 1024 + gcol];
  const unsigned short* gbB = &Wt[(size_t)grow * 1024 + gcol];
  char* laB = (char*)As + (w * 32) * 128;
  char* lbB = (char*)Bs + (w * 32) * 128;

  for (int k0 = 0; k0 < 1024; k0 += 64) {
    __syncthreads();                 // prev window's ds_reads complete
#pragma unroll
    for (int i = 0; i < 4; ++i) {
      gl16(gaB + (size_t)i * 8 * 1024 + k0, laB + i * 1024);
      gl16(gbB + (size_t)i * 8 * 1024 + k0, lbB + i * 1024);
    }
    __syncthreads();                 // drains vmcnt: tiles visible

    // t==2: compute (W^T * emb^T) = V^T directly by swapping operand roles.
    const unsigned short* PA = (t == 2) ? Bs : As;
    const unsigned short* PB = (t == 2) ? As : Bs;

#pragma unroll
    for (int kk = 0; kk < 2; ++kk) {
      const int slot = ((kk * 4 + q4) ^ x7) * 8;
      bf16x8 af[4], bfr[4];
#pragma unroll
      for (int ms = 0; ms < 4; ++ms)
        af[ms] = *(const bf16x8*)&PA[((w >> 1) * 64 + ms * 16 + l16) * 64 + slot];
#pragma unroll
      for (int js = 0; js < 4; ++js)
        bfr[js] = *(const bf16x8*)&PB[((w & 1) * 64 + js * 16 + l16) * 64 + slot];
      __builtin_amdgcn_s_setprio(1);
#pragma unroll
      for (int ms = 0; ms < 4; ++ms)
#pragma unroll
        for (int js = 0; js < 4; ++js)
          acc[ms][js] = MFMA16(af[ms], bfr[js], acc[ms][js]);
      __builtin_amdgcn_s_setprio(0);
    }
  }

  if (t < 2) {
    unsigned short* outp = (t == 0) ? QG : KG;
    const float osc = (t == 0) ? (0.125f * LOG2E) : 1.0f;  // fold softmax scale into Q
    const int h = (n0 >> 6) + (w & 1);
    const size_t hb = (size_t)(b * 16 + h) * 2048;
#pragma unroll
    for (int ms = 0; ms < 4; ++ms)
#pragma unroll
      for (int js = 0; js < 4; ++js) {
        const int c = js * 16 + l16;
#pragma unroll
        for (int r = 0; r < 4; ++r) {
          const int s = sloc + (w >> 1) * 64 + ms * 16 + q4 * 4 + r;
          outp[(hb + s) * 64 + c] = f2bf(acc[ms][js][r] * osc);
        }
      }
  } else {
    const int h = (n0 >> 6) + (w >> 1);
    const size_t hb = (size_t)(b * 16 + h) * 64;
#pragma unroll
    for (int ms = 0; ms < 4; ++ms)
#pragma unroll
      for (int js = 0; js < 4; ++js) {
        const int s = sloc + (w & 1) * 64 + js * 16 + l16;
#pragma unroll
        for (int r = 0; r < 4; ++r) {
          const int c = ms * 16 + q4 * 4 + r;
          VtG[(hb + c) * 2048 + s] = f2bf(acc[ms][js][r]);
        }
      }
  }
}

// ---------------------------------------------------------------------------
// Flash attention, causal. Grid (16*nb bh, 16 y), 512 thr (8 waves).
// Block owns ONE 128-row q-tile t (y->t CU-balancing swizzle); wave w owns
// rows q0+16w..+15. Iterations per block = 2t+2; each CU's 4 resident
// blocks sum to 68 iters. Swapped-operand S^T = mfma(K,Q); softmax row is
// lane-local (q=l16). Deferred l-sum: per-lane partial, epilogue reduce.
// LDS XOR-swizzle: Ks/Vs/Plds linear 64-short rows; 16B-slot ^= (row&7) on
// write and read -> conflict-free. Offsets loop-invariant per thread.
// ---------------------------------------------------------------------------
__global__ __launch_bounds__(512)
void flash_kernel(const unsigned short* __restrict__ QG,
                  const unsigned short* __restrict__ KG,
                  const unsigned short* __restrict__ VtG,
                  unsigned short* __restrict__ ObG) {
  const int bh = blockIdx.x;
  const int y = blockIdx.y;                 // 0..15
  const int k4 = y >> 2, y0 = y & 3;
  const int t = k4 + 4 * ((y0 + k4) & 3);   // CU-balancing bijective swizzle
  const int q0 = t * 128;
  const int tid = threadIdx.x;
  const int lane = tid & 63, w = tid >> 6;  // w in 0..7
  const int wp = w & 3;
  const int q4 = lane >> 4, l16 = lane & 15;
  const int qw = q0 + w * 16;               // wave's first q-row
  const int jlim = q0 + ((w >= 4) ? 64 : 0);  // last j-tile this wave computes
  const int jlimB = q0 + 64;                  // block's last j-tile

  const unsigned short* Qp = QG + ((size_t)bh * 2048 + qw) * 64;
  const unsigned short* Kp = KG + (size_t)bh * 2048 * 64;
  const unsigned short* Vp = VtG + (size_t)bh * 64 * 2048;

  // B-fragment of Q for S^T mfma: lane holds Q[q=l16][d=q4*8..+8] (pre-scaled)
  const bf16x8 qf0 = *(const bf16x8*)&Qp[(size_t)l16 * 64 + q4 * 8];
  const bf16x8 qf1 = *(const bf16x8*)&Qp[(size_t)l16 * 64 + 32 + q4 * 8];

  __shared__ __align__(16) unsigned short Ks[64 * 64];       // [s][d] swizzled
  __shared__ __align__(16) unsigned short Vs[64 * 64];       // [dv][s] swizzled
  __shared__ __align__(16) unsigned short Plds[8 * 16 * 64]; // per-wave P[q][k] swz

  f32x4 oacc[4] = {};  // O^T: oacc[js][r] = O[q=l16][dv=js*16+q4*4+r]
  float m_i = BIG_NEG, l_part = 0.f;  // l_part: this lane's 16-col partial

  // staging: 512 threads, one 16B K-slice + one 16B V-slice each.
  // LDS dest: row sr, slot (tid&7)^(sr&7)  (XOR swizzle, loop-invariant)
  const int sr = tid >> 3, sc = (tid & 7) * 8;
  const int sdst = sr * 64 + (((tid & 7) ^ (sr & 7)) * 8);
  u32x4 kreg = *(const u32x4*)&Kp[(size_t)sr * 64 + sc];
  u32x4 vreg = *(const u32x4*)&Vp[(size_t)sr * 2048 + sc];

  // loop-invariant swizzled read offsets (row&7 == l16&7 for all fragment rows)
  const int x7 = l16 & 7;
  const int ks0 = (q4 ^ x7) * 8;            // K/V slot for first 32 shorts
  const int ks1 = ((4 + q4) ^ x7) * 8;      // ... second 32 shorts
  const int prow = (w * 16 + l16) * 64;     // this lane's P row base

  for (int j0 = 0; j0 <= jlimB; j0 += 64) {
    *(u32x4*)&Ks[sdst] = kreg;
    *(u32x4*)&Vs[sdst] = vreg;
    __syncthreads();

    // prefetch next tile into regs; overlaps with the compute below (T14)
    if (j0 + 64 <= jlimB) {
      const int jn = j0 + 64;
      kreg = *(const u32x4*)&Kp[(size_t)(jn + sr) * 64 + sc];
      vreg = *(const u32x4*)&Vp[(size_t)sr * 2048 + jn + sc];
    }

    if (j0 <= jlim) {  // wave-uniform: this wave still has causal work
      // S^T tile: sacc[js][r] = S[q=l16][k = js*16 + q4*4 + r] (log2 domain)
      f32x4 sacc[4] = {};
      __builtin_amdgcn_s_setprio(1);
#pragma unroll
      for (int js = 0; js < 4; ++js) {
        const int krow = (js * 16 + l16) * 64;
        const bf16x8 kf0 = *(const bf16x8*)&Ks[krow + ks0];
        const bf16x8 kf1 = *(const bf16x8*)&Ks[krow + ks1];
        sacc[js] = MFMA16(kf0, qf0, sacc[js]);
        sacc[js] = MFMA16(kf1, qf1, sacc[js]);
      }
      __builtin_amdgcn_s_setprio(0);

      // causal mask (edge tile only) + in-lane max
      float mloc = BIG_NEG;
      if (j0 == jlim) {
        const int qrel = wp * 16 + l16;  // wave's row offset within this j-tile
#pragma unroll
        for (int js = 0; js < 4; ++js)
#pragma unroll
          for (int r = 0; r < 4; ++r) {
            const int krel = js * 16 + q4 * 4 + r;
            float v = sacc[js][r];
            if (krel > qrel) v = BIG_NEG;
            sacc[js][r] = v;
            mloc = fmaxf(mloc, v);
          }
      } else {
#pragma unroll
        for (int js = 0; js < 4; ++js)
#pragma unroll
          for (int r = 0; r < 4; ++r) mloc = fmaxf(mloc, sacc[js][r]);
      }
      // row max across the 4 q4-groups sharing q=l16
      mloc = fmaxf(mloc, __shfl_xor(mloc, 16, 64));
      mloc = fmaxf(mloc, __shfl_xor(mloc, 32, 64));

      // defer-max (T13): only rescale when the running max grew past THR
      if (__any(mloc > m_i + DEFER_THR)) {
        const float mnew = fmaxf(m_i, mloc);
        const float alpha = __builtin_amdgcn_exp2f(m_i - mnew);
        m_i = mnew;
        l_part *= alpha;
#pragma unroll
        for (int js = 0; js < 4; ++js)
#pragma unroll
          for (int r = 0; r < 4; ++r) oacc[js][r] *= alpha;
      }

#pragma unroll
      for (int js = 0; js < 4; ++js)
#pragma unroll
        for (int r = 0; r < 4; ++r) {
          const float p = __builtin_amdgcn_exp2f(sacc[js][r] - m_i);
          sacc[js][r] = p;
          l_part += p;  // sum reduce deferred to epilogue
        }

      // P store: row q=l16; 8B at swizzled slot js*2+(q4>>1) ^ x7
#pragma unroll
      for (int js = 0; js < 4; ++js) {
        u32x2 pk;
        pk[0] = cvtpk(sacc[js][0], sacc[js][1]);
        pk[1] = cvtpk(sacc[js][2], sacc[js][3]);
        const int pslot = (((js * 2 + (q4 >> 1)) ^ x7) * 8) + ((q4 & 1) * 4);
        *(u32x2*)&Plds[prow + pslot] = pk;
      }

      asm volatile("" ::: "memory");

      // B-fragment of P^T: lane needs P[q=l16][k=q4*8..+8] (swizzled slots)
      const bf16x8 pf0 = *(const bf16x8*)&Plds[prow + ks0];
      const bf16x8 pf1 = *(const bf16x8*)&Plds[prow + ks1];

      __builtin_amdgcn_s_setprio(1);
#pragma unroll
      for (int js = 0; js < 4; ++js) {
        const int vrow = (js * 16 + l16) * 64;
        const bf16x8 vf0 = *(const bf16x8*)&Vs[vrow + ks0];
        const bf16x8 vf1 = *(const bf16x8*)&Vs[vrow + ks1];
        oacc[js] = MFMA16(vf0, pf0, oacc[js]);
        oacc[js] = MFMA16(vf1, pf1, oacc[js]);
      }
      __builtin_amdgcn_s_setprio(0);
    }
    __syncthreads();  // all LDS reads done before next iter's staging writes
  }

  // epilogue: reduce deferred l across the 4 q4-groups, then write O.
  float l_i = l_part;
  l_i += __shfl_xor(l_i, 16, 64);
  l_i += __shfl_xor(l_i, 32, 64);

  // concat-head layout ObG[b][s][h*64+dv]; 4 consecutive dv per 8B store
  const int b = bh >> 4, h = bh & 15;
  const int q = qw + l16;
  const float rl = 1.0f / l_i;
  unsigned short* orow = ObG + ((size_t)b * 2048 + q) * 1024 + h * 64;
#pragma unroll
  for (int js = 0; js < 4; ++js) {
    u32x2 ok;
    ok[0] = cvtpk(oacc[js][0] * rl, oacc[js][1] * rl);
    ok[1] = cvtpk(oacc[js][2] * rl, oacc[js][3] * rl);
    *(u32x2*)&orow[js * 16 + q4 * 4] = ok;
  }
}

// ---------------------------------------------------------------------------
// Output projection, GROUP: ObG bf16 [nb*2048][1024] x WoT bf16 [n][d]
// + bo(f32) -> outG f32 [nb*2048][1024].
// 1D grid nwg = 8*MB_CNT, XCD-chunked swizzle, m-major. BK=64 with
// pre-swizzled gl16 source + swizzled fragment reads (same as qkv).
// ---------------------------------------------------------------------------
__global__ __launch_bounds__(256)
void oproj_kernel(const unsigned short* __restrict__ ObG,
                  const unsigned short* __restrict__ WoT,
                  const float* __restrict__ bo,
                  float* __restrict__ outG) {
  const int nwg = gridDim.x;                       // 8 * MB_CNT, %8 == 0
  const int wg = blockIdx.x;
  const int swz = (wg & 7) * (nwg >> 3) + (wg >> 3);
  const int m0 = (swz >> 3) * 128;
  const int n0 = (swz & 7) * 128;

  __shared__ __align__(16) unsigned short As[128 * 64];
  __shared__ __align__(16) unsigned short Bs[128 * 64];

  const int tid = threadIdx.x;
  const int lane = tid & 63, w = tid >> 6;
  const int q4 = lane >> 4, l16 = lane & 15;
  const int x7 = l16 & 7;

  f32x4 acc[4][4] = {};

  const int grow = w * 32 + (lane >> 3);
  const int gcol = (((lane & 7) ^ ((lane >> 3) & 7)) * 8);
  const unsigned short* gaB = &ObG[(size_t)(m0 + grow) * 1024 + gcol];
  const unsigned short* gbB = &WoT[(size_t)(n0 + grow) * 1024 + gcol];
  char* laB = (char*)As + (w * 32) * 128;
  char* lbB = (char*)Bs + (w * 32) * 128;

  for (int k0 = 0; k0 < 1024; k0 += 64) {
    __syncthreads();
#pragma unroll
    for (int i = 0; i < 4; ++i) {
      gl16(gaB + (size_t)i * 8 * 1024 + k0, laB + i * 1024);
      gl16(gbB + (size_t)i * 8 * 1024 + k0, lbB + i * 1024);
    }
    __syncthreads();

#pragma unroll
    for (int kk = 0; kk < 2; ++kk) {
      const int slot = ((kk * 4 + q4) ^ x7) * 8;
      bf16x8 af[4], bfr[4];
#pragma unroll
      for (int ms = 0; ms < 4; ++ms)
        af[ms] = *(const bf16x8*)&As[((w >> 1) * 64 + ms * 16 + l16) * 64 + slot];
#pragma unroll
      for (int js = 0; js < 4; ++js)
        bfr[js] = *(const bf16x8*)&Bs[((w & 1) * 64 + js * 16 + l16) * 64 + slot];
      __builtin_amdgcn_s_setprio(1);
#pragma unroll
      for (int ms = 0; ms < 4; ++ms)
#pragma unroll
        for (int js = 0; js < 4; ++js)
          acc[ms][js] = MFMA16(af[ms], bfr[js], acc[ms][js]);
      __builtin_amdgcn_s_setprio(0);
    }
  }

#pragma unroll
  for (int js = 0; js < 4; ++js) {
    const int col = n0 + (w & 1) * 64 + js * 16 + l16;
    const float bias = bo[col];
#pragma unroll
    for (int ms = 0; ms < 4; ++ms)
#pragma unroll
      for (int r = 0; r < 4; ++r) {
        const int row = m0 + (w >> 1) * 64 + ms * 16 + q4 * 4 + r;
        outG[(size_t)row * 1024 + col] = acc[ms][js][r] + bias;  // f32 store
      }
  }
}

// ---------------------------------------------------------------------------
extern "C" void kernel_launch(void* const* d_in, const int* in_sizes, int n_in,
                              void* d_out, int out_size, void* d_ws, size_t ws_size,
                              hipStream_t stream) {
  const float* emb = (const float*)d_in[0];   // [4][2048][1024] f32
  const float* Wq  = (const float*)d_in[1];   // [16][1024][64]  f32
  const float* Wk  = (const float*)d_in[2];
  const float* Wv  = (const float*)d_in[3];
  const float* Wo  = (const float*)d_in[4];   // [1024][1024]    f32
  const float* bo  = (const float*)d_in[5];   // [1024]          f32
  float* out = (float*)d_out;                 // [4][2048][1024] f32

  char* ws = (char*)d_ws;
  const size_t MB = 1024 * 1024;

  // group size: nb batches per pipeline pass. ws need = 8 + 16*nb MB.
  const int nb = (ws_size >= 72 * MB) ? 4 : (ws_size >= 40 * MB) ? 2 : 1;

  unsigned short* WqT = (unsigned short*)(ws + 0 * MB);              // 2 MB [h][c][d]
  unsigned short* WkT = (unsigned short*)(ws + 2 * MB);              // 2 MB
  unsigned short* WvT = (unsigned short*)(ws + 4 * MB);              // 2 MB
  unsigned short* WoT = (unsigned short*)(ws + 6 * MB);              // 2 MB [n][d]
  unsigned short* QG  = (unsigned short*)(ws + 8 * MB);              // 4*nb MB
  unsigned short* KG  = (unsigned short*)(ws + (8 + 4 * nb) * MB);   // 4*nb MB
  unsigned short* VtG = (unsigned short*)(ws + (8 + 8 * nb) * MB);   // 4*nb MB
  unsigned short* ObG = (unsigned short*)(ws + (8 + 12 * nb) * MB);  // 4*nb MB

  const dim3 tb(32, 8, 1);
  wtrans3_kernel<<<dim3(2, 32, 48), tb, 0, stream>>>(Wq, Wk, Wv, WqT, WkT, WvT);
  wtrans_kernel<<<dim3(32, 32, 1), tb, 0, stream>>>(Wo, WoT, 1024, 1024);

  for (int g = 0; g < 4; g += nb) {
    const float* embG = emb + (size_t)g * 2048 * 1024;
    float* outG = out + (size_t)g * 2048 * 1024;
    // embB (bf16 emb) aliases ObG: dead before flash writes ObG, per group.
    unsigned short* embB = ObG;
    embconv_kernel<<<dim3(nb * 1024), 256, 0, stream>>>(embG, embB);
    qkv_kernel<<<dim3(24 * 16 * nb), 256, 0, stream>>>(embB, WqT, WkT, WvT, QG, KG, VtG);
    flash_kernel<<<dim3(16 * nb, 16), 512, 0, stream>>>(QG, KG, VtG, ObG);
    oproj_kernel<<<dim3(8 * 16 * nb), 256, 0, stream>>>(ObG, WoT, bo, outG);
  }
}

// Round 11
// 248.193 us; speedup vs baseline: 1.2834x; 1.0095x over previous
//
#include <hip/hip_runtime.h>
#include <hip/hip_bf16.h>

// B=4, S=2048, D=1024, H=16, DK=DV=64. Inputs f32, output f32 (confirmed r8).
// MFMA math bf16 with f32 accum. Round 20 (base: r19 = 250.6 us):
//  - flash ONLY: in-loop __syncthreads() replaced with raw s_barrier +
//    lgkmcnt(0)-only waits (m201/T4 pattern); K/V prefetch issued BEFORE the
//    barrier so global loads stay in flight across it. Removes the per-iter
//    vmcnt(0) drain that was serializing the T14 prefetch into the barrier.
//  - qkv/oproj/embconv/wtrans: unchanged from r19.

typedef __attribute__((ext_vector_type(8))) short bf16x8;
typedef __attribute__((ext_vector_type(4))) float f32x4;
typedef __attribute__((ext_vector_type(4))) unsigned int u32x4;
typedef __attribute__((ext_vector_type(2))) unsigned int u32x2;

#define MFMA16(a, b, c) __builtin_amdgcn_mfma_f32_16x16x32_bf16((a), (b), (c), 0, 0, 0)

#define LOG2E 1.44269504088896340736f
#define BIG_NEG (-3.0e38f)
#define DEFER_THR 10.0f  // log2-domain; P bounded by 2^10 when rescale skipped

__device__ __forceinline__ unsigned short f2bf(float f) {
  union { float f; unsigned int i; } x; x.f = f;
  unsigned int lsb = (x.i >> 16) & 1;
  x.i += 0x7fffu + lsb;  // RNE (finite inputs only)
  return (unsigned short)(x.i >> 16);
}

__device__ __forceinline__ unsigned int cvtpk(float lo, float hi) {
  unsigned int r;
  asm("v_cvt_pk_bf16_f32 %0, %1, %2" : "=v"(r) : "v"(lo), "v"(hi));
  return r;
}

// global -> LDS direct DMA, 16B per lane. lds dest must be wave-uniform base;
// HW writes base + lane*16. Global src is per-lane.
__device__ __forceinline__ void gl16(const unsigned short* g, void* l) {
  __builtin_amdgcn_global_load_lds(
      (const __attribute__((address_space(1))) unsigned int*)g,
      (__attribute__((address_space(3))) unsigned int*)l, 16, 0, 0);
}

// LDS-only barrier: orders DS ops block-wide WITHOUT draining vmcnt —
// in-flight global prefetch loads cross it untouched (AITER/T4 pattern).
__device__ __forceinline__ void lds_barrier() {
  asm volatile("s_waitcnt lgkmcnt(0)" ::: "memory");
  __builtin_amdgcn_s_barrier();
  __builtin_amdgcn_sched_barrier(0);
}

// ---------------------------------------------------------------------------
// Transpose + downconvert for Wq/Wk/Wv in ONE launch: z = which*16 + head.
// in f32 [16][1024][64] -> out bf16 [16][64][1024]
// ---------------------------------------------------------------------------
__global__ void wtrans3_kernel(const float* __restrict__ Wq,
                               const float* __restrict__ Wk,
                               const float* __restrict__ Wv,
                               unsigned short* __restrict__ Oq,
                               unsigned short* __restrict__ Ok,
                               unsigned short* __restrict__ Ov) {
  __shared__ unsigned short tile[32][33];
  const int bz = blockIdx.z;              // 0..47
  const int which = bz >> 4, h = bz & 15;
  const float* ip = (which == 0 ? Wq : which == 1 ? Wk : Wv) + (size_t)h * 1024 * 64;
  unsigned short* op = (which == 0 ? Oq : which == 1 ? Ok : Ov) + (size_t)h * 1024 * 64;
  const int c0 = blockIdx.x * 32, r0 = blockIdx.y * 32;
  const int tx = threadIdx.x, ty = threadIdx.y;  // (32, 8)
#pragma unroll
  for (int i = 0; i < 32; i += 8)
    tile[ty + i][tx] = f2bf(ip[(size_t)(r0 + ty + i) * 64 + (c0 + tx)]);
  __syncthreads();
#pragma unroll
  for (int i = 0; i < 32; i += 8)
    op[(size_t)(c0 + ty + i) * 1024 + (r0 + tx)] = tile[tx][ty + i];
}

// Wo transpose: in f32 [1024][1024] -> out bf16 [1024][1024]^T
__global__ void wtrans_kernel(const float* __restrict__ in,
                              unsigned short* __restrict__ out, int R, int C) {
  __shared__ unsigned short tile[32][33];
  const int c0 = blockIdx.x * 32, r0 = blockIdx.y * 32;
  const int tx = threadIdx.x, ty = threadIdx.y;  // (32, 8)
#pragma unroll
  for (int i = 0; i < 32; i += 8)
    tile[ty + i][tx] = f2bf(in[(size_t)(r0 + ty + i) * C + (c0 + tx)]);
  __syncthreads();
#pragma unroll
  for (int i = 0; i < 32; i += 8)
    out[(size_t)(c0 + ty + i) * R + (r0 + tx)] = tile[tx][ty + i];
}

// ---------------------------------------------------------------------------
// f32 -> bf16 bulk convert (emb). Grid covers exactly n/8 threads.
// ---------------------------------------------------------------------------
__global__ __launch_bounds__(256)
void embconv_kernel(const float* __restrict__ in, unsigned short* __restrict__ out) {
  const int i = blockIdx.x * 256 + threadIdx.x;
  const float4 a = ((const float4*)in)[2 * i];
  const float4 b = ((const float4*)in)[2 * i + 1];
  union { unsigned short u[8]; u32x4 v; } p;
  p.u[0] = f2bf(a.x); p.u[1] = f2bf(a.y); p.u[2] = f2bf(a.z); p.u[3] = f2bf(a.w);
  p.u[4] = f2bf(b.x); p.u[5] = f2bf(b.y); p.u[6] = f2bf(b.z); p.u[7] = f2bf(b.w);
  ((u32x4*)out)[i] = p.v;
}

// ---------------------------------------------------------------------------
// QKV projection, GROUP of nb batches: embB bf16 [nb*2048][1024] x WtT bf16
// [h][c][d] -> Q (pre-scaled by 0.125*log2e), K bf16 [(b*16+h)][s][64],
// V transposed -> Vt [(b*16+h)][dv][s].
// 1D grid nwg = 24*MB_CNT, XCD-chunked swizzle, m-major block order.
// BK=64. Staging: gl16 with PRE-SWIZZLED global source (lane l loads col
// chunk (l&7)^((l>>3)&7)) -> LDS holds chunk c at slot c^(row&7). Fragment
// reads use slot (kk*4+q4)^(l16&7): conflict-free, loop-invariant.
// ---------------------------------------------------------------------------
__global__ __launch_bounds__(256)
void qkv_kernel(const unsigned short* __restrict__ embB,
                const unsigned short* __restrict__ WqT,
                const unsigned short* __restrict__ WkT,
                const unsigned short* __restrict__ WvT,
                unsigned short* __restrict__ QG,
                unsigned short* __restrict__ KG,
                unsigned short* __restrict__ VtG) {
  const int nwg = gridDim.x;                       // 24 * MB_CNT, %8 == 0
  const int wg = blockIdx.x;
  const int swz = (wg & 7) * (nwg >> 3) + (wg >> 3);
  const int mb = swz / 24;                         // embB panel index
  const int rem = swz - mb * 24;
  const int t = rem >> 3;                          // 0=Q, 1=K, 2=V
  const int m0 = mb * 128;
  const int n0 = (rem & 7) * 128;
  const int b = m0 >> 11;                          // local batch
  const int sloc = m0 & 2047;
  const unsigned short* Wt =
      (t == 0 ? WqT : (t == 1 ? WkT : WvT)) + (size_t)(n0 >> 6) * 64 * 1024;

  __shared__ __align__(16) unsigned short As[128 * 64];  // [m][64] swizzled slots
  __shared__ __align__(16) unsigned short Bs[128 * 64];  // [n][64] swizzled slots

  const int tid = threadIdx.x;
  const int lane = tid & 63, w = tid >> 6;
  const int q4 = lane >> 4, l16 = lane & 15;
  const int x7 = l16 & 7;

  f32x4 acc[4][4] = {};

  // staging: wave w covers rows [w*32, w*32+32) of both 128x64 tiles.
  // gl16 i stages rows w*32+i*8+(lane>>3); lane loads pre-swizzled col chunk.
  const int grow = w * 32 + (lane >> 3);
  const int gcol = (((lane & 7) ^ ((lane >> 3) & 7)) * 8);
  const unsigned short* gaB = &embB[(size_t)(m0 + grow) * 1024 + gcol];
  const unsigned short* gbB = &Wt[(size_t)grow * 1024 + gcol];
  char* laB = (char*)As + (w * 32) * 128;
  char* lbB = (char*)Bs + (w * 32) * 128;

  for (int k0 = 0; k0 < 1024; k0 += 64) {
    __syncthreads();                 // prev window's ds_reads complete
#pragma unroll
    for (int i = 0; i < 4; ++i) {
      gl16(gaB + (size_t)i * 8 * 1024 + k0, laB + i * 1024);
      gl16(gbB + (size_t)i * 8 * 1024 + k0, lbB + i * 1024);
    }
    __syncthreads();                 // drains vmcnt: tiles visible

    // t==2: compute (W^T * emb^T) = V^T directly by swapping operand roles.
    const unsigned short* PA = (t == 2) ? Bs : As;
    const unsigned short* PB = (t == 2) ? As : Bs;

#pragma unroll
    for (int kk = 0; kk < 2; ++kk) {
      const int slot = ((kk * 4 + q4) ^ x7) * 8;
      bf16x8 af[4], bfr[4];
#pragma unroll
      for (int ms = 0; ms < 4; ++ms)
        af[ms] = *(const bf16x8*)&PA[((w >> 1) * 64 + ms * 16 + l16) * 64 + slot];
#pragma unroll
      for (int js = 0; js < 4; ++js)
        bfr[js] = *(const bf16x8*)&PB[((w & 1) * 64 + js * 16 + l16) * 64 + slot];
      __builtin_amdgcn_s_setprio(1);
#pragma unroll
      for (int ms = 0; ms < 4; ++ms)
#pragma unroll
        for (int js = 0; js < 4; ++js)
          acc[ms][js] = MFMA16(af[ms], bfr[js], acc[ms][js]);
      __builtin_amdgcn_s_setprio(0);
    }
  }

  if (t < 2) {
    unsigned short* outp = (t == 0) ? QG : KG;
    const float osc = (t == 0) ? (0.125f * LOG2E) : 1.0f;  // fold softmax scale into Q
    const int h = (n0 >> 6) + (w & 1);
    const size_t hb = (size_t)(b * 16 + h) * 2048;
#pragma unroll
    for (int ms = 0; ms < 4; ++ms)
#pragma unroll
      for (int js = 0; js < 4; ++js) {
        const int c = js * 16 + l16;
#pragma unroll
        for (int r = 0; r < 4; ++r) {
          const int s = sloc + (w >> 1) * 64 + ms * 16 + q4 * 4 + r;
          outp[(hb + s) * 64 + c] = f2bf(acc[ms][js][r] * osc);
        }
      }
  } else {
    const int h = (n0 >> 6) + (w >> 1);
    const size_t hb = (size_t)(b * 16 + h) * 64;
#pragma unroll
    for (int ms = 0; ms < 4; ++ms)
#pragma unroll
      for (int js = 0; js < 4; ++js) {
        const int s = sloc + (w & 1) * 64 + js * 16 + l16;
#pragma unroll
        for (int r = 0; r < 4; ++r) {
          const int c = ms * 16 + q4 * 4 + r;
          VtG[(hb + c) * 2048 + s] = f2bf(acc[ms][js][r]);
        }
      }
  }
}

// ---------------------------------------------------------------------------
// Flash attention, causal. Grid (16*nb bh, 16 y), 512 thr (8 waves).
// Block owns ONE 128-row q-tile t (y->t CU-balancing swizzle); wave w owns
// rows q0+16w..+15. Iterations per block = 2t+2; each CU's 4 resident
// blocks sum to 68 iters. Swapped-operand S^T = mfma(K,Q); softmax row is
// lane-local (q=l16). Deferred l-sum: per-lane partial, epilogue reduce.
// LDS XOR-swizzle (conflict-free). In-loop barriers are lgkm-only raw
// s_barrier: K/V prefetch loads stay in flight across them (no vmcnt drain).
// ---------------------------------------------------------------------------
__global__ __launch_bounds__(512)
void flash_kernel(const unsigned short* __restrict__ QG,
                  const unsigned short* __restrict__ KG,
                  const unsigned short* __restrict__ VtG,
                  unsigned short* __restrict__ ObG) {
  const int bh = blockIdx.x;
  const int y = blockIdx.y;                 // 0..15
  const int k4 = y >> 2, y0 = y & 3;
  const int t = k4 + 4 * ((y0 + k4) & 3);   // CU-balancing bijective swizzle
  const int q0 = t * 128;
  const int tid = threadIdx.x;
  const int lane = tid & 63, w = tid >> 6;  // w in 0..7
  const int wp = w & 3;
  const int q4 = lane >> 4, l16 = lane & 15;
  const int qw = q0 + w * 16;               // wave's first q-row
  const int jlim = q0 + ((w >= 4) ? 64 : 0);  // last j-tile this wave computes
  const int jlimB = q0 + 64;                  // block's last j-tile

  const unsigned short* Qp = QG + ((size_t)bh * 2048 + qw) * 64;
  const unsigned short* Kp = KG + (size_t)bh * 2048 * 64;
  const unsigned short* Vp = VtG + (size_t)bh * 64 * 2048;

  // B-fragment of Q for S^T mfma: lane holds Q[q=l16][d=q4*8..+8] (pre-scaled)
  const bf16x8 qf0 = *(const bf16x8*)&Qp[(size_t)l16 * 64 + q4 * 8];
  const bf16x8 qf1 = *(const bf16x8*)&Qp[(size_t)l16 * 64 + 32 + q4 * 8];

  __shared__ __align__(16) unsigned short Ks[64 * 64];       // [s][d] swizzled
  __shared__ __align__(16) unsigned short Vs[64 * 64];       // [dv][s] swizzled
  __shared__ __align__(16) unsigned short Plds[8 * 16 * 64]; // per-wave P[q][k] swz

  f32x4 oacc[4] = {};  // O^T: oacc[js][r] = O[q=l16][dv=js*16+q4*4+r]
  float m_i = BIG_NEG, l_part = 0.f;  // l_part: this lane's 16-col partial

  // staging: 512 threads, one 16B K-slice + one 16B V-slice each.
  // LDS dest: row sr, slot (tid&7)^(sr&7)  (XOR swizzle, loop-invariant)
  const int sr = tid >> 3, sc = (tid & 7) * 8;
  const int sdst = sr * 64 + (((tid & 7) ^ (sr & 7)) * 8);
  u32x4 kreg = *(const u32x4*)&Kp[(size_t)sr * 64 + sc];
  u32x4 vreg = *(const u32x4*)&Vp[(size_t)sr * 2048 + sc];

  // loop-invariant swizzled read offsets (row&7 == l16&7 for all fragment rows)
  const int x7 = l16 & 7;
  const int ks0 = (q4 ^ x7) * 8;            // K/V slot for first 32 shorts
  const int ks1 = ((4 + q4) ^ x7) * 8;      // ... second 32 shorts
  const int prow = (w * 16 + l16) * 64;     // this lane's P row base

  for (int j0 = 0; j0 <= jlimB; j0 += 64) {
    // ds_write waits (reg dependency) only on our own 2 loads, then issue
    // next prefetch BEFORE the barrier so it spans the whole iteration.
    *(u32x4*)&Ks[sdst] = kreg;
    *(u32x4*)&Vs[sdst] = vreg;
    if (j0 + 64 <= jlimB) {
      const int jn = j0 + 64;
      kreg = *(const u32x4*)&Kp[(size_t)(jn + sr) * 64 + sc];
      vreg = *(const u32x4*)&Vp[(size_t)sr * 2048 + jn + sc];
    }
    lds_barrier();   // staging visible; prefetch loads remain in flight

    if (j0 <= jlim) {  // wave-uniform: this wave still has causal work
      // S^T tile: sacc[js][r] = S[q=l16][k = js*16 + q4*4 + r] (log2 domain)
      f32x4 sacc[4] = {};
      __builtin_amdgcn_s_setprio(1);
#pragma unroll
      for (int js = 0; js < 4; ++js) {
        const int krow = (js * 16 + l16) * 64;
        const bf16x8 kf0 = *(const bf16x8*)&Ks[krow + ks0];
        const bf16x8 kf1 = *(const bf16x8*)&Ks[krow + ks1];
        sacc[js] = MFMA16(kf0, qf0, sacc[js]);
        sacc[js] = MFMA16(kf1, qf1, sacc[js]);
      }
      __builtin_amdgcn_s_setprio(0);

      // causal mask (edge tile only) + in-lane max
      float mloc = BIG_NEG;
      if (j0 == jlim) {
        const int qrel = wp * 16 + l16;  // wave's row offset within this j-tile
#pragma unroll
        for (int js = 0; js < 4; ++js)
#pragma unroll
          for (int r = 0; r < 4; ++r) {
            const int krel = js * 16 + q4 * 4 + r;
            float v = sacc[js][r];
            if (krel > qrel) v = BIG_NEG;
            sacc[js][r] = v;
            mloc = fmaxf(mloc, v);
          }
      } else {
#pragma unroll
        for (int js = 0; js < 4; ++js)
#pragma unroll
          for (int r = 0; r < 4; ++r) mloc = fmaxf(mloc, sacc[js][r]);
      }
      // row max across the 4 q4-groups sharing q=l16
      mloc = fmaxf(mloc, __shfl_xor(mloc, 16, 64));
      mloc = fmaxf(mloc, __shfl_xor(mloc, 32, 64));

      // defer-max (T13): only rescale when the running max grew past THR
      if (__any(mloc > m_i + DEFER_THR)) {
        const float mnew = fmaxf(m_i, mloc);
        const float alpha = __builtin_amdgcn_exp2f(m_i - mnew);
        m_i = mnew;
        l_part *= alpha;
#pragma unroll
        for (int js = 0; js < 4; ++js)
#pragma unroll
          for (int r = 0; r < 4; ++r) oacc[js][r] *= alpha;
      }

#pragma unroll
      for (int js = 0; js < 4; ++js)
#pragma unroll
        for (int r = 0; r < 4; ++r) {
          const float p = __builtin_amdgcn_exp2f(sacc[js][r] - m_i);
          sacc[js][r] = p;
          l_part += p;  // sum reduce deferred to epilogue
        }

      // P store: row q=l16; 8B at swizzled slot js*2+(q4>>1) ^ x7
#pragma unroll
      for (int js = 0; js < 4; ++js) {
        u32x2 pk;
        pk[0] = cvtpk(sacc[js][0], sacc[js][1]);
        pk[1] = cvtpk(sacc[js][2], sacc[js][3]);
        const int pslot = (((js * 2 + (q4 >> 1)) ^ x7) * 8) + ((q4 & 1) * 4);
        *(u32x2*)&Plds[prow + pslot] = pk;
      }

      asm volatile("" ::: "memory");

      // B-fragment of P^T: lane needs P[q=l16][k=q4*8..+8] (swizzled slots)
      const bf16x8 pf0 = *(const bf16x8*)&Plds[prow + ks0];
      const bf16x8 pf1 = *(const bf16x8*)&Plds[prow + ks1];

      __builtin_amdgcn_s_setprio(1);
#pragma unroll
      for (int js = 0; js < 4; ++js) {
        const int vrow = (js * 16 + l16) * 64;
        const bf16x8 vf0 = *(const bf16x8*)&Vs[vrow + ks0];
        const bf16x8 vf1 = *(const bf16x8*)&Vs[vrow + ks1];
        oacc[js] = MFMA16(vf0, pf0, oacc[js]);
        oacc[js] = MFMA16(vf1, pf1, oacc[js]);
      }
      __builtin_amdgcn_s_setprio(0);
    }
    lds_barrier();   // all waves' LDS reads done; prefetch still in flight
  }

  // epilogue: reduce deferred l across the 4 q4-groups, then write O.
  float l_i = l_part;
  l_i += __shfl_xor(l_i, 16, 64);
  l_i += __shfl_xor(l_i, 32, 64);

  // concat-head layout ObG[b][s][h*64+dv]; 4 consecutive dv per 8B store
  const int b = bh >> 4, h = bh & 15;
  const int q = qw + l16;
  const float rl = 1.0f / l_i;
  unsigned short* orow = ObG + ((size_t)b * 2048 + q) * 1024 + h * 64;
#pragma unroll
  for (int js = 0; js < 4; ++js) {
    u32x2 ok;
    ok[0] = cvtpk(oacc[js][0] * rl, oacc[js][1] * rl);
    ok[1] = cvtpk(oacc[js][2] * rl, oacc[js][3] * rl);
    *(u32x2*)&orow[js * 16 + q4 * 4] = ok;
  }
}

// ---------------------------------------------------------------------------
// Output projection, GROUP: ObG bf16 [nb*2048][1024] x WoT bf16 [n][d]
// + bo(f32) -> outG f32 [nb*2048][1024].
// 1D grid nwg = 8*MB_CNT, XCD-chunked swizzle, m-major. BK=64 with
// pre-swizzled gl16 source + swizzled fragment reads (same as qkv).
// ---------------------------------------------------------------------------
__global__ __launch_bounds__(256)
void oproj_kernel(const unsigned short* __restrict__ ObG,
                  const unsigned short* __restrict__ WoT,
                  const float* __restrict__ bo,
                  float* __restrict__ outG) {
  const int nwg = gridDim.x;                       // 8 * MB_CNT, %8 == 0
  const int wg = blockIdx.x;
  const int swz = (wg & 7) * (nwg >> 3) + (wg >> 3);
  const int m0 = (swz >> 3) * 128;
  const int n0 = (swz & 7) * 128;

  __shared__ __align__(16) unsigned short As[128 * 64];
  __shared__ __align__(16) unsigned short Bs[128 * 64];

  const int tid = threadIdx.x;
  const int lane = tid & 63, w = tid >> 6;
  const int q4 = lane >> 4, l16 = lane & 15;
  const int x7 = l16 & 7;

  f32x4 acc[4][4] = {};

  const int grow = w * 32 + (lane >> 3);
  const int gcol = (((lane & 7) ^ ((lane >> 3) & 7)) * 8);
  const unsigned short* gaB = &ObG[(size_t)(m0 + grow) * 1024 + gcol];
  const unsigned short* gbB = &WoT[(size_t)(n0 + grow) * 1024 + gcol];
  char* laB = (char*)As + (w * 32) * 128;
  char* lbB = (char*)Bs + (w * 32) * 128;

  for (int k0 = 0; k0 < 1024; k0 += 64) {
    __syncthreads();
#pragma unroll
    for (int i = 0; i < 4; ++i) {
      gl16(gaB + (size_t)i * 8 * 1024 + k0, laB + i * 1024);
      gl16(gbB + (size_t)i * 8 * 1024 + k0, lbB + i * 1024);
    }
    __syncthreads();

#pragma unroll
    for (int kk = 0; kk < 2; ++kk) {
      const int slot = ((kk * 4 + q4) ^ x7) * 8;
      bf16x8 af[4], bfr[4];
#pragma unroll
      for (int ms = 0; ms < 4; ++ms)
        af[ms] = *(const bf16x8*)&As[((w >> 1) * 64 + ms * 16 + l16) * 64 + slot];
#pragma unroll
      for (int js = 0; js < 4; ++js)
        bfr[js] = *(const bf16x8*)&Bs[((w & 1) * 64 + js * 16 + l16) * 64 + slot];
      __builtin_amdgcn_s_setprio(1);
#pragma unroll
      for (int ms = 0; ms < 4; ++ms)
#pragma unroll
        for (int js = 0; js < 4; ++js)
          acc[ms][js] = MFMA16(af[ms], bfr[js], acc[ms][js]);
      __builtin_amdgcn_s_setprio(0);
    }
  }

#pragma unroll
  for (int js = 0; js < 4; ++js) {
    const int col = n0 + (w & 1) * 64 + js * 16 + l16;
    const float bias = bo[col];
#pragma unroll
    for (int ms = 0; ms < 4; ++ms)
#pragma unroll
      for (int r = 0; r < 4; ++r) {
        const int row = m0 + (w >> 1) * 64 + ms * 16 + q4 * 4 + r;
        outG[(size_t)row * 1024 + col] = acc[ms][js][r] + bias;  // f32 store
      }
  }
}

// ---------------------------------------------------------------------------
extern "C" void kernel_launch(void* const* d_in, const int* in_sizes, int n_in,
                              void* d_out, int out_size, void* d_ws, size_t ws_size,
                              hipStream_t stream) {
  const float* emb = (const float*)d_in[0];   // [4][2048][1024] f32
  const float* Wq  = (const float*)d_in[1];   // [16][1024][64]  f32
  const float* Wk  = (const float*)d_in[2];
  const float* Wv  = (const float*)d_in[3];
  const float* Wo  = (const float*)d_in[4];   // [1024][1024]    f32
  const float* bo  = (const float*)d_in[5];   // [1024]          f32
  float* out = (float*)d_out;                 // [4][2048][1024] f32

  char* ws = (char*)d_ws;
  const size_t MB = 1024 * 1024;

  // group size: nb batches per pipeline pass. ws need = 8 + 16*nb MB.
  const int nb = (ws_size >= 72 * MB) ? 4 : (ws_size >= 40 * MB) ? 2 : 1;

  unsigned short* WqT = (unsigned short*)(ws + 0 * MB);              // 2 MB [h][c][d]
  unsigned short* WkT = (unsigned short*)(ws + 2 * MB);              // 2 MB
  unsigned short* WvT = (unsigned short*)(ws + 4 * MB);              // 2 MB
  unsigned short* WoT = (unsigned short*)(ws + 6 * MB);              // 2 MB [n][d]
  unsigned short* QG  = (unsigned short*)(ws + 8 * MB);              // 4*nb MB
  unsigned short* KG  = (unsigned short*)(ws + (8 + 4 * nb) * MB);   // 4*nb MB
  unsigned short* VtG = (unsigned short*)(ws + (8 + 8 * nb) * MB);   // 4*nb MB
  unsigned short* ObG = (unsigned short*)(ws + (8 + 12 * nb) * MB);  // 4*nb MB

  const dim3 tb(32, 8, 1);
  wtrans3_kernel<<<dim3(2, 32, 48), tb, 0, stream>>>(Wq, Wk, Wv, WqT, WkT, WvT);
  wtrans_kernel<<<dim3(32, 32, 1), tb, 0, stream>>>(Wo, WoT, 1024, 1024);

  for (int g = 0; g < 4; g += nb) {
    const float* embG = emb + (size_t)g * 2048 * 1024;
    float* outG = out + (size_t)g * 2048 * 1024;
    // embB (bf16 emb) aliases ObG: dead before flash writes ObG, per group.
    unsigned short* embB = ObG;
    embconv_kernel<<<dim3(nb * 1024), 256, 0, stream>>>(embG, embB);
    qkv_kernel<<<dim3(24 * 16 * nb), 256, 0, stream>>>(embB, WqT, WkT, WvT, QG, KG, VtG);
    flash_kernel<<<dim3(16 * nb, 16), 512, 0, stream>>>(QG, KG, VtG, ObG);
    oproj_kernel<<<dim3(8 * 16 * nb), 256, 0, stream>>>(ObG, WoT, bo, outG);
  }
}